// Round 1
// baseline (430.335 us; speedup 1.0000x reference)
//
#include <hip/hip_runtime.h>
#include <hip/hip_bf16.h>
#include <stdint.h>

// Problem dims (fixed)
#define B_    32
#define S_    2048
#define ENC_  1024
#define DEC_  1024
#define M_    (B_*S_)   // 65536

typedef __attribute__((ext_vector_type(8))) short bf16x8;
typedef __attribute__((ext_vector_type(4))) float f32x4;

__device__ __forceinline__ unsigned short f2bf(float f) {
  unsigned u = __builtin_bit_cast(unsigned, f);
  u += 0x7FFFu + ((u >> 16) & 1u);            // RNE
  return (unsigned short)(u >> 16);
}
__device__ __forceinline__ float bf2f(unsigned short u) {
  unsigned x = ((unsigned)u) << 16;
  return __builtin_bit_cast(float, x);
}
__device__ __forceinline__ void async_copy16(void* lds_dst, const void* g_src) {
  __builtin_amdgcn_global_load_lds(
      (const __attribute__((address_space(1))) void*)g_src,
      (__attribute__((address_space(3))) void*)lds_dst, 16, 0, 0);
}
// tanh via exp2-based __expf; saturates correctly at +/-inf
__device__ __forceinline__ float tanh_fast(float x) {
  return 1.f - 2.f / (__expf(2.f * x) + 1.f);
}

// ---------- kernel 1: enc f32 -> bf16 ----------
__global__ __launch_bounds__(256) void cvt_enc_kernel(
    const float4* __restrict__ in, ushort4* __restrict__ out, int n4) {
  int idx = blockIdx.x * blockDim.x + threadIdx.x;
  int stride = gridDim.x * blockDim.x;
  for (int i = idx; i < n4; i += stride) {
    float4 f = in[i];
    ushort4 o;
    o.x = f2bf(f.x); o.y = f2bf(f.y); o.z = f2bf(f.z); o.w = f2bf(f.w);
    out[i] = o;
  }
}

// ---------- kernel 2: W[e][d] f32 -> Wt[d][e] bf16 (transpose+convert) ----------
__global__ void wt_kernel(const float* __restrict__ W, unsigned short* __restrict__ Wt) {
  __shared__ float tile[32][33];
  const int e0 = blockIdx.x * 32, d0 = blockIdx.y * 32;
  const int tx = threadIdx.x, ty = threadIdx.y;   // (32,8)
  #pragma unroll
  for (int i = 0; i < 4; ++i)
    tile[ty + i*8][tx] = W[(size_t)(e0 + ty + i*8) * DEC_ + d0 + tx];
  __syncthreads();
  #pragma unroll
  for (int i = 0; i < 4; ++i)
    Wt[(size_t)(d0 + ty + i*8) * ENC_ + e0 + tx] = f2bf(tile[tx][ty + i*8]);
}

// ---------- kernel 3: t[b][d] = dec[b,:] @ U[:,d] (f32), e-split + atomics ----------
__global__ __launch_bounds__(128) void t_kernel(
    const float* __restrict__ dec, const float* __restrict__ U, float* __restrict__ t) {
  __shared__ float decs[B_ * 256];   // 32KB: dec[:, e0:e0+256]
  const int tid = threadIdx.x;
  const int d  = blockIdx.x * 128 + tid;   // [0,1024)
  const int e0 = blockIdx.y * 256;         // [0,1024) step 256
  for (int i = tid; i < B_ * 256 / 4; i += 128) {
    int b  = (i * 4) >> 8;
    int ee = (i * 4) & 255;
    *(float4*)&decs[b * 256 + ee] = *(const float4*)&dec[(size_t)b * DEC_ + e0 + ee];
  }
  __syncthreads();
  float acc[B_] = {};
  for (int e = 0; e < 256; ++e) {
    float u = U[(size_t)(e0 + e) * DEC_ + d];
    #pragma unroll
    for (int b = 0; b < B_; ++b) acc[b] += decs[b * 256 + e] * u;
  }
  #pragma unroll
  for (int b = 0; b < B_; ++b) atomicAdd(&t[b * DEC_ + d], acc[b]);
}

// ---------- kernel 4: fused scores GEMM ----------
// scores[m] += sum_{n in tile} v[n]*tanh( (A@Wt^T)[m,n] + t[b,n] )
// A: enc16 [65536][1024] bf16, Bt: Wt [1024(n)][1024(k)] bf16
__global__ __launch_bounds__(256) void scores_kernel(
    const unsigned short* __restrict__ A,
    const unsigned short* __restrict__ Bt,
    const float* __restrict__ tb,
    const float* __restrict__ v,
    float* __restrict__ scores)
{
  __shared__ unsigned short As[128 * 64];   // 16KB
  __shared__ unsigned short Bs[128 * 64];   // 16KB
  __shared__ float sloc[128];

  const int tid  = threadIdx.x;
  const int lane = tid & 63;
  const int w    = tid >> 6;
  const int wr = w >> 1, wc = w & 1;
  const int fr = lane & 15, fq = lane >> 4;

  const int m0 = blockIdx.x * 128;
  const int n0 = blockIdx.y * 128;
  const int b  = m0 >> 11;   // 2048 % 128 == 0 -> single batch per tile

  if (tid < 128) sloc[tid] = 0.f;

  f32x4 acc[4][4] = {};

  const int grow = lane >> 3;        // within-chunk row (8 rows per 1KB chunk)
  const int gcol = (lane & 7) * 8;   // k-col (8 bf16 = 16B per lane)

  for (int k0 = 0; k0 < ENC_; k0 += 64) {
    __syncthreads();
    #pragma unroll
    for (int i = 0; i < 4; ++i) {
      const int c = i * 4 + w;       // chunk 0..15, 1KB each
      async_copy16((char*)As + c * 1024,
                   A  + (size_t)(m0 + c * 8 + grow) * ENC_ + k0 + gcol);
      async_copy16((char*)Bs + c * 1024,
                   Bt + (size_t)(n0 + c * 8 + grow) * ENC_ + k0 + gcol);
    }
    asm volatile("s_waitcnt vmcnt(0)" ::: "memory");
    __syncthreads();
    #pragma unroll
    for (int kk = 0; kk < 2; ++kk) {
      bf16x8 af[4], bfr[4];
      #pragma unroll
      for (int mi = 0; mi < 4; ++mi)
        af[mi] = *reinterpret_cast<const bf16x8*>(&As[(wr*64 + mi*16 + fr)*64 + kk*32 + fq*8]);
      #pragma unroll
      for (int ni = 0; ni < 4; ++ni)
        bfr[ni] = *reinterpret_cast<const bf16x8*>(&Bs[(wc*64 + ni*16 + fr)*64 + kk*32 + fq*8]);
      #pragma unroll
      for (int mi = 0; mi < 4; ++mi)
        #pragma unroll
        for (int ni = 0; ni < 4; ++ni)
          acc[mi][ni] = __builtin_amdgcn_mfma_f32_16x16x32_bf16(af[mi], bfr[ni], acc[mi][ni], 0, 0, 0);
    }
  }

  // epilogue: C/D layout col=lane&15, row=fq*4+j (verified m89/m91)
  float vv[4], tv[4];
  #pragma unroll
  for (int ni = 0; ni < 4; ++ni) {
    int col = n0 + wc*64 + ni*16 + fr;
    vv[ni] = v[col];
    tv[ni] = tb[b * DEC_ + col];
  }
  #pragma unroll
  for (int mi = 0; mi < 4; ++mi) {
    #pragma unroll
    for (int j = 0; j < 4; ++j) {
      float p = 0.f;
      #pragma unroll
      for (int ni = 0; ni < 4; ++ni)
        p += vv[ni] * tanh_fast(acc[mi][ni][j] + tv[ni]);
      p += __shfl_xor(p, 1);
      p += __shfl_xor(p, 2);
      p += __shfl_xor(p, 4);
      p += __shfl_xor(p, 8);
      if (fr == 0) atomicAdd(&sloc[wr*64 + mi*16 + fq*4 + j], p);
    }
  }
  __syncthreads();
  if (tid < 128) atomicAdd(&scores[m0 + tid], sloc[tid]);
}

// ---------- kernel 5: masked softmax over S per batch ----------
__global__ __launch_bounds__(256) void softmax_kernel(
    const float* __restrict__ scores, const int* __restrict__ mask,
    float* __restrict__ attn) {
  const int b = blockIdx.x;
  const int tid = threadIdx.x;
  const int lane = tid & 63, w = tid >> 6;
  __shared__ float wred[4];
  float loc[8];
  float mx = -3.0e38f;
  #pragma unroll
  for (int i = 0; i < 8; ++i) {
    int s = tid + i * 256;
    float val = (mask[b * S_ + s] == 0) ? -1e9f : scores[b * S_ + s];
    loc[i] = val;
    mx = fmaxf(mx, val);
  }
  #pragma unroll
  for (int m = 1; m < 64; m <<= 1) mx = fmaxf(mx, __shfl_xor(mx, m));
  if (lane == 0) wred[w] = mx;
  __syncthreads();
  mx = fmaxf(fmaxf(wred[0], wred[1]), fmaxf(wred[2], wred[3]));
  __syncthreads();
  float sum = 0.f;
  #pragma unroll
  for (int i = 0; i < 8; ++i) { loc[i] = __expf(loc[i] - mx); sum += loc[i]; }
  #pragma unroll
  for (int m = 1; m < 64; m <<= 1) sum += __shfl_xor(sum, m);
  if (lane == 0) wred[w] = sum;
  __syncthreads();
  float inv = 1.f / (wred[0] + wred[1] + wred[2] + wred[3]);
  #pragma unroll
  for (int i = 0; i < 8; ++i) attn[b * S_ + tid + i * 256] = loc[i] * inv;
}

// ---------- kernel 6: context[b,e] = sum_s attn[b,s]*enc[b,s,e], s-split + atomics ----------
__global__ __launch_bounds__(256) void ctx_kernel(
    const unsigned short* __restrict__ enc16,
    const float* __restrict__ attn,
    float* __restrict__ ctx) {
  const int b  = blockIdx.x;
  const int s0 = blockIdx.y * 128;
  const int tid = threadIdx.x;
  const ushort4* base = reinterpret_cast<const ushort4*>(
      enc16 + ((size_t)b * S_ + s0) * ENC_) + tid;
  float a0 = 0.f, a1 = 0.f, a2 = 0.f, a3 = 0.f;
  for (int s = 0; s < 128; ++s) {
    float a = attn[b * S_ + s0 + s];
    ushort4 ev = base[(size_t)s * 256];
    a0 += a * bf2f(ev.x); a1 += a * bf2f(ev.y);
    a2 += a * bf2f(ev.z); a3 += a * bf2f(ev.w);
  }
  float* c = ctx + (size_t)b * ENC_ + tid * 4;
  atomicAdd(c + 0, a0); atomicAdd(c + 1, a1);
  atomicAdd(c + 2, a2); atomicAdd(c + 3, a3);
}

extern "C" void kernel_launch(void* const* d_in, const int* in_sizes, int n_in,
                              void* d_out, int out_size, void* d_ws, size_t ws_size,
                              hipStream_t stream) {
  const float* enc  = (const float*)d_in[0];   // [32,2048,1024]
  const float* dec  = (const float*)d_in[1];   // [32,1024]
  const int*   mask = (const int*)  d_in[2];   // [32,2048]
  const float* W    = (const float*)d_in[3];   // [1024,1024]
  const float* U    = (const float*)d_in[4];   // [1024,1024]
  const float* v    = (const float*)d_in[5];   // [1024]

  float* out  = (float*)d_out;
  float* ctx  = out;                 // [32,1024]
  float* attn = out + B_ * ENC_;     // [32,2048]

  char* ws = (char*)d_ws;
  unsigned short* enc16 = (unsigned short*)ws;                         // 128MB
  unsigned short* Wt    = (unsigned short*)(ws + (size_t)M_ * ENC_ * 2);          // 2MB
  float* t_buf  = (float*)(ws + (size_t)M_ * ENC_ * 2 + (size_t)ENC_ * DEC_ * 2); // 128KB
  float* scores = (float*)((char*)t_buf + (size_t)B_ * DEC_ * 4);                 // 256KB

  hipMemsetAsync(scores, 0, (size_t)M_ * 4, stream);
  hipMemsetAsync(t_buf, 0, (size_t)B_ * DEC_ * 4, stream);
  hipMemsetAsync(ctx, 0, (size_t)B_ * ENC_ * 4, stream);

  cvt_enc_kernel<<<8192, 256, 0, stream>>>(
      (const float4*)enc, (ushort4*)enc16, M_ * ENC_ / 4);
  wt_kernel<<<dim3(ENC_ / 32, DEC_ / 32), dim3(32, 8), 0, stream>>>(W, Wt);
  t_kernel<<<dim3(DEC_ / 128, 4), 128, 0, stream>>>(dec, U, t_buf);

  scores_kernel<<<dim3(M_ / 128, DEC_ / 128), 256, 0, stream>>>(
      enc16, Wt, t_buf, v, scores);

  softmax_kernel<<<B_, 256, 0, stream>>>(scores, mask, attn);

  ctx_kernel<<<dim3(B_, S_ / 128), 256, 0, stream>>>(enc16, attn, ctx);
}

// Round 2
// 352.002 us; speedup vs baseline: 1.2225x; 1.2225x over previous
//
#include <hip/hip_runtime.h>
#include <hip/hip_bf16.h>
#include <stdint.h>

// Problem dims (fixed)
#define B_    32
#define S_    2048
#define ENC_  1024
#define DEC_  1024
#define M_    (B_*S_)   // 65536

typedef __attribute__((ext_vector_type(8))) short bf16x8;
typedef __attribute__((ext_vector_type(4))) float f32x4;

__device__ __forceinline__ unsigned short f2bf(float f) {
  unsigned u = __builtin_bit_cast(unsigned, f);
  u += 0x7FFFu + ((u >> 16) & 1u);            // RNE
  return (unsigned short)(u >> 16);
}
__device__ __forceinline__ float bf2f(unsigned short u) {
  unsigned x = ((unsigned)u) << 16;
  return __builtin_bit_cast(float, x);
}
__device__ __forceinline__ void async_copy16(void* lds_dst, const void* g_src) {
  __builtin_amdgcn_global_load_lds(
      (const __attribute__((address_space(1))) void*)g_src,
      (__attribute__((address_space(3))) void*)lds_dst, 16, 0, 0);
}
__device__ __forceinline__ float tanh_fast(float x) {
  return 1.f - 2.f / (__expf(2.f * x) + 1.f);
}

// ---------- kernel 1: enc f32 -> bf16 ----------
__global__ __launch_bounds__(256) void cvt_enc_kernel(
    const float4* __restrict__ in, ushort4* __restrict__ out, int n4) {
  int idx = blockIdx.x * blockDim.x + threadIdx.x;
  int stride = gridDim.x * blockDim.x;
  for (int i = idx; i < n4; i += stride) {
    float4 f = in[i];
    ushort4 o;
    o.x = f2bf(f.x); o.y = f2bf(f.y); o.z = f2bf(f.z); o.w = f2bf(f.w);
    out[i] = o;
  }
}

// ---------- kernel 2: W[e][d] f32 -> Wt[d][e] bf16 (transpose+convert) ----------
__global__ void wt_kernel(const float* __restrict__ W, unsigned short* __restrict__ Wt) {
  __shared__ float tile[32][33];
  const int e0 = blockIdx.x * 32, d0 = blockIdx.y * 32;
  const int tx = threadIdx.x, ty = threadIdx.y;   // (32,8)
  #pragma unroll
  for (int i = 0; i < 4; ++i)
    tile[ty + i*8][tx] = W[(size_t)(e0 + ty + i*8) * DEC_ + d0 + tx];
  __syncthreads();
  #pragma unroll
  for (int i = 0; i < 4; ++i)
    Wt[(size_t)(d0 + ty + i*8) * ENC_ + e0 + tx] = f2bf(tile[tx][ty + i*8]);
}

// ---------- kernel 3: t[b][d] = dec[b,:] @ U[:,d] (f32), e-split + atomics ----------
__global__ __launch_bounds__(128) void t_kernel(
    const float* __restrict__ dec, const float* __restrict__ U, float* __restrict__ t) {
  __shared__ float decs[B_ * 256];   // 32KB
  const int tid = threadIdx.x;
  const int d  = blockIdx.x * 128 + tid;
  const int e0 = blockIdx.y * 256;
  for (int i = tid; i < B_ * 256 / 4; i += 128) {
    int b  = (i * 4) >> 8;
    int ee = (i * 4) & 255;
    *(float4*)&decs[b * 256 + ee] = *(const float4*)&dec[(size_t)b * DEC_ + e0 + ee];
  }
  __syncthreads();
  float acc[B_] = {};
  for (int e = 0; e < 256; ++e) {
    float u = U[(size_t)(e0 + e) * DEC_ + d];
    #pragma unroll
    for (int b = 0; b < B_; ++b) acc[b] += decs[b * 256 + e] * u;
  }
  #pragma unroll
  for (int b = 0; b < B_; ++b) atomicAdd(&t[b * DEC_ + d], acc[b]);
}

// ---------- kernel 4: fused scores GEMM, 256x128x64 pipelined ----------
// 512 threads = 8 waves (4M x 2N), per-wave C = 64x64.
// LDS: 3 buffers x (A 256x64 bf16 = 32KB + B 128x64 bf16 = 16KB) = 144KB.
// T2 swizzle: physical 16B-slot = logical_slot ^ (row&7); global source
// pre-swizzled so global_load_lds (linear dest) lands data swizzled.
__global__ __launch_bounds__(512, 2) void scores_kernel(
    const unsigned short* __restrict__ A,     // enc16 [65536][1024]
    const unsigned short* __restrict__ Bt,    // Wt [1024 n][1024 k]
    const float* __restrict__ tb,
    const float* __restrict__ v,
    float* __restrict__ scores)
{
  extern __shared__ char lds[];

  const int tid  = threadIdx.x;
  const int lane = tid & 63;
  const int wid  = tid >> 6;
  const int wr = wid >> 1, wc = wid & 1;        // 4M x 2N wave grid
  const int fr = lane & 15, fq = lane >> 4;

  // XCD-aware swizzle: 8 consecutive logical ids (the 8 n-blocks of one
  // m-panel) land on one XCD -> enc panel shared in that XCD's L2.
  const int bid = blockIdx.x;                   // 2048 blocks, 2048%8==0
  const int logical = (bid & 7) * 256 + (bid >> 3);
  const int m_blk = logical >> 3, n_blk = logical & 7;
  const int m0 = m_blk << 8;                    // 256 rows
  const int n0 = n_blk << 7;                    // 128 cols
  const int b  = m_blk >> 3;                    // batch (2048 rows/batch)

  // ---- staging source addressing (pre-swizzled global source) ----
  const int srow   = tid >> 3;                          // 0..63 row within round
  const int kchunk = (((tid & 7) ^ (srow & 7)) << 3);   // element offset of 16B chunk
  const unsigned short* a0 = A  + (size_t)(m0       + srow) * ENC_ + kchunk;
  const unsigned short* a1 = A  + (size_t)(m0 + 64  + srow) * ENC_ + kchunk;
  const unsigned short* a2 = A  + (size_t)(m0 + 128 + srow) * ENC_ + kchunk;
  const unsigned short* a3 = A  + (size_t)(m0 + 192 + srow) * ENC_ + kchunk;
  const unsigned short* b0 = Bt + (size_t)(n0       + srow) * ENC_ + kchunk;
  const unsigned short* b1 = Bt + (size_t)(n0 + 64  + srow) * ENC_ + kchunk;
  const int wbase = wid * 1024;                 // wave-uniform LDS dest base

  // ---- fragment read addressing (swizzled) ----
  const int aRB = (wr * 64 + fr) * 128;           // + mi*2048 + slot
  const int bRB = 32768 + (wc * 64 + fr) * 128;   // + ni*2048 + slot
  const int sl0 = ((fq)     ^ (fr & 7)) << 4;     // kk=0 slot bytes
  const int sl1 = ((4 + fq) ^ (fr & 7)) << 4;     // kk=1 slot bytes

  f32x4 acc[4][4] = {};

  // ---- prologue: stage tiles 0 (buf0) and 1 (buf1) ----
  async_copy16(lds +         0 * 8192 + wbase, a0);
  async_copy16(lds +         1 * 8192 + wbase, a1);
  async_copy16(lds +         2 * 8192 + wbase, a2);
  async_copy16(lds +         3 * 8192 + wbase, a3);
  async_copy16(lds + 32768 + 0 * 8192 + wbase, b0);
  async_copy16(lds + 32768 + 1 * 8192 + wbase, b1);
  async_copy16(lds + 49152 +         0 * 8192 + wbase, a0 + 64);
  async_copy16(lds + 49152 +         1 * 8192 + wbase, a1 + 64);
  async_copy16(lds + 49152 +         2 * 8192 + wbase, a2 + 64);
  async_copy16(lds + 49152 +         3 * 8192 + wbase, a3 + 64);
  async_copy16(lds + 49152 + 32768 + 0 * 8192 + wbase, b0 + 64);
  async_copy16(lds + 49152 + 32768 + 1 * 8192 + wbase, b1 + 64);
  asm volatile("s_waitcnt vmcnt(6)" ::: "memory");   // tile 0 landed
  asm volatile("s_barrier" ::: "memory");

  int cur = 0;
  #pragma unroll 1
  for (int t = 0; t < 16; ++t) {
    const int rb = cur * 49152;                        // read buffer
    const int pbuf = (cur >= 1) ? cur - 1 : 2;         // (cur+2)%3
    const int pb = pbuf * 49152;
    const int ko = (t + 2) * 64;                       // prefetch K offset
    const bool pf = (t < 14);

    // ---------------- phase 0 (kk = 0) ----------------
    if (pf) {
      async_copy16(lds + pb + 0 * 8192 + wbase, a0 + ko);
      async_copy16(lds + pb + 1 * 8192 + wbase, a1 + ko);
      async_copy16(lds + pb + 2 * 8192 + wbase, a2 + ko);
    }
    {
      bf16x8 af[4], bff[4];
      #pragma unroll
      for (int mi = 0; mi < 4; ++mi)
        af[mi] = *reinterpret_cast<const bf16x8*>(lds + rb + aRB + mi * 2048 + sl0);
      #pragma unroll
      for (int ni = 0; ni < 4; ++ni)
        bff[ni] = *reinterpret_cast<const bf16x8*>(lds + rb + bRB + ni * 2048 + sl0);
      __builtin_amdgcn_s_setprio(1);
      #pragma unroll
      for (int mi = 0; mi < 4; ++mi)
        #pragma unroll
        for (int ni = 0; ni < 4; ++ni)
          acc[mi][ni] = __builtin_amdgcn_mfma_f32_16x16x32_bf16(af[mi], bff[ni], acc[mi][ni], 0, 0, 0);
      __builtin_amdgcn_s_setprio(0);
    }
    asm volatile("s_waitcnt lgkmcnt(0)\n\ts_barrier" ::: "memory");

    // ---------------- phase 1 (kk = 1) ----------------
    if (pf) {
      async_copy16(lds + pb + 3 * 8192 + wbase, a3 + ko);
      async_copy16(lds + pb + 32768 + 0 * 8192 + wbase, b0 + ko);
      async_copy16(lds + pb + 32768 + 1 * 8192 + wbase, b1 + ko);
    }
    {
      bf16x8 af[4], bff[4];
      #pragma unroll
      for (int mi = 0; mi < 4; ++mi)
        af[mi] = *reinterpret_cast<const bf16x8*>(lds + rb + aRB + mi * 2048 + sl1);
      #pragma unroll
      for (int ni = 0; ni < 4; ++ni)
        bff[ni] = *reinterpret_cast<const bf16x8*>(lds + rb + bRB + ni * 2048 + sl1);
      __builtin_amdgcn_s_setprio(1);
      #pragma unroll
      for (int mi = 0; mi < 4; ++mi)
        #pragma unroll
        for (int ni = 0; ni < 4; ++ni)
          acc[mi][ni] = __builtin_amdgcn_mfma_f32_16x16x32_bf16(af[mi], bff[ni], acc[mi][ni], 0, 0, 0);
      __builtin_amdgcn_s_setprio(0);
    }
    // tile boundary: keep tile t+2's 6 loads in flight; require tile t+1 landed
    if (t < 14) {
      asm volatile("s_waitcnt lgkmcnt(0) vmcnt(6)\n\ts_barrier" ::: "memory");
    } else if (t == 14) {
      asm volatile("s_waitcnt lgkmcnt(0) vmcnt(0)\n\ts_barrier" ::: "memory");
    }
    cur = (cur == 2) ? 0 : cur + 1;
  }

  // ---- epilogue: v-dot of tanh(acc + t), row-reduce, atomic to scores ----
  asm volatile("s_waitcnt vmcnt(0) lgkmcnt(0)\n\ts_barrier" ::: "memory");
  float* sloc = (float*)lds;
  if (tid < 256) sloc[tid] = 0.f;
  __syncthreads();

  float vv[4], tv[4];
  #pragma unroll
  for (int ni = 0; ni < 4; ++ni) {
    int col = n0 + wc * 64 + ni * 16 + fr;
    vv[ni] = v[col];
    tv[ni] = tb[b * DEC_ + col];
  }
  #pragma unroll
  for (int mi = 0; mi < 4; ++mi) {
    #pragma unroll
    for (int j = 0; j < 4; ++j) {
      float p = 0.f;
      #pragma unroll
      for (int ni = 0; ni < 4; ++ni)
        p += vv[ni] * tanh_fast(acc[mi][ni][j] + tv[ni]);
      p += __shfl_xor(p, 1);
      p += __shfl_xor(p, 2);
      p += __shfl_xor(p, 4);
      p += __shfl_xor(p, 8);
      if (fr == 0) atomicAdd(&sloc[wr * 64 + mi * 16 + fq * 4 + j], p);
    }
  }
  __syncthreads();
  if (tid < 256) atomicAdd(&scores[m0 + tid], sloc[tid]);
}

// ---------- kernel 5: masked softmax over S per batch ----------
__global__ __launch_bounds__(256) void softmax_kernel(
    const float* __restrict__ scores, const int* __restrict__ mask,
    float* __restrict__ attn) {
  const int b = blockIdx.x;
  const int tid = threadIdx.x;
  const int lane = tid & 63, w = tid >> 6;
  __shared__ float wred[4];
  float loc[8];
  float mx = -3.0e38f;
  #pragma unroll
  for (int i = 0; i < 8; ++i) {
    int s = tid + i * 256;
    float val = (mask[b * S_ + s] == 0) ? -1e9f : scores[b * S_ + s];
    loc[i] = val;
    mx = fmaxf(mx, val);
  }
  #pragma unroll
  for (int m = 1; m < 64; m <<= 1) mx = fmaxf(mx, __shfl_xor(mx, m));
  if (lane == 0) wred[w] = mx;
  __syncthreads();
  mx = fmaxf(fmaxf(wred[0], wred[1]), fmaxf(wred[2], wred[3]));
  __syncthreads();
  float sum = 0.f;
  #pragma unroll
  for (int i = 0; i < 8; ++i) { loc[i] = __expf(loc[i] - mx); sum += loc[i]; }
  #pragma unroll
  for (int m = 1; m < 64; m <<= 1) sum += __shfl_xor(sum, m);
  if (lane == 0) wred[w] = sum;
  __syncthreads();
  float inv = 1.f / (wred[0] + wred[1] + wred[2] + wred[3]);
  #pragma unroll
  for (int i = 0; i < 8; ++i) attn[b * S_ + tid + i * 256] = loc[i] * inv;
}

// ---------- kernel 6: context[b,e] = sum_s attn[b,s]*enc[b,s,e] ----------
__global__ __launch_bounds__(256) void ctx_kernel(
    const unsigned short* __restrict__ enc16,
    const float* __restrict__ attn,
    float* __restrict__ ctx) {
  const int b  = blockIdx.x;
  const int s0 = blockIdx.y * 128;
  const int tid = threadIdx.x;
  const ushort4* base = reinterpret_cast<const ushort4*>(
      enc16 + ((size_t)b * S_ + s0) * ENC_) + tid;
  float a0 = 0.f, a1 = 0.f, a2 = 0.f, a3 = 0.f;
  for (int s = 0; s < 128; ++s) {
    float a = attn[b * S_ + s0 + s];
    ushort4 ev = base[(size_t)s * 256];
    a0 += a * bf2f(ev.x); a1 += a * bf2f(ev.y);
    a2 += a * bf2f(ev.z); a3 += a * bf2f(ev.w);
  }
  float* c = ctx + (size_t)b * ENC_ + tid * 4;
  atomicAdd(c + 0, a0); atomicAdd(c + 1, a1);
  atomicAdd(c + 2, a2); atomicAdd(c + 3, a3);
}

extern "C" void kernel_launch(void* const* d_in, const int* in_sizes, int n_in,
                              void* d_out, int out_size, void* d_ws, size_t ws_size,
                              hipStream_t stream) {
  const float* enc  = (const float*)d_in[0];
  const float* dec  = (const float*)d_in[1];
  const int*   mask = (const int*)  d_in[2];
  const float* W    = (const float*)d_in[3];
  const float* U    = (const float*)d_in[4];
  const float* v    = (const float*)d_in[5];

  float* out  = (float*)d_out;
  float* ctx  = out;
  float* attn = out + B_ * ENC_;

  char* ws = (char*)d_ws;
  unsigned short* enc16 = (unsigned short*)ws;                                    // 128MB
  unsigned short* Wt    = (unsigned short*)(ws + (size_t)M_ * ENC_ * 2);          // 2MB
  float* t_buf  = (float*)(ws + (size_t)M_ * ENC_ * 2 + (size_t)ENC_ * DEC_ * 2); // 128KB
  float* scores = (float*)((char*)t_buf + (size_t)B_ * DEC_ * 4);                 // 256KB

  // allow 144KB dynamic LDS (idempotent; ignore errors during capture)
  (void)hipFuncSetAttribute((const void*)scores_kernel,
                            hipFuncAttributeMaxDynamicSharedMemorySize, 147456);

  hipMemsetAsync(scores, 0, (size_t)M_ * 4, stream);
  hipMemsetAsync(t_buf, 0, (size_t)B_ * DEC_ * 4, stream);
  hipMemsetAsync(ctx, 0, (size_t)B_ * ENC_ * 4, stream);

  cvt_enc_kernel<<<8192, 256, 0, stream>>>(
      (const float4*)enc, (ushort4*)enc16, M_ * ENC_ / 4);
  wt_kernel<<<dim3(ENC_ / 32, DEC_ / 32), dim3(32, 8), 0, stream>>>(W, Wt);
  t_kernel<<<dim3(DEC_ / 128, 4), 128, 0, stream>>>(dec, U, t_buf);

  scores_kernel<<<2048, 512, 147456, stream>>>(enc16, Wt, t_buf, v, scores);

  softmax_kernel<<<B_, 256, 0, stream>>>(scores, mask, attn);

  ctx_kernel<<<dim3(B_, S_ / 128), 256, 0, stream>>>(enc16, attn, ctx);
}

// Round 3
// 334.023 us; speedup vs baseline: 1.2883x; 1.0538x over previous
//
#include <hip/hip_runtime.h>
#include <hip/hip_bf16.h>
#include <stdint.h>

// Problem dims (fixed)
#define B_    32
#define S_    2048
#define ENC_  1024
#define DEC_  1024
#define M_    (B_*S_)   // 65536

typedef __attribute__((ext_vector_type(8))) short bf16x8;
typedef __attribute__((ext_vector_type(4))) float f32x4;

__device__ __forceinline__ unsigned short f2bf(float f) {
  unsigned u = __builtin_bit_cast(unsigned, f);
  u += 0x7FFFu + ((u >> 16) & 1u);            // RNE
  return (unsigned short)(u >> 16);
}
__device__ __forceinline__ float bf2f(unsigned short u) {
  unsigned x = ((unsigned)u) << 16;
  return __builtin_bit_cast(float, x);
}
__device__ __forceinline__ void async_copy16(void* lds_dst, const void* g_src) {
  __builtin_amdgcn_global_load_lds(
      (const __attribute__((address_space(1))) void*)g_src,
      (__attribute__((address_space(3))) void*)lds_dst, 16, 0, 0);
}
__device__ __forceinline__ float tanh_fast(float x) {
  return 1.f - 2.f / (__expf(2.f * x) + 1.f);
}

// ---------- kernel 1: enc f32 -> bf16 ----------
__global__ __launch_bounds__(256) void cvt_enc_kernel(
    const float4* __restrict__ in, ushort4* __restrict__ out, int n4) {
  int idx = blockIdx.x * blockDim.x + threadIdx.x;
  int stride = gridDim.x * blockDim.x;
  for (int i = idx; i < n4; i += stride) {
    float4 f = in[i];
    ushort4 o;
    o.x = f2bf(f.x); o.y = f2bf(f.y); o.z = f2bf(f.z); o.w = f2bf(f.w);
    out[i] = o;
  }
}

// ---------- kernel 2: W[e][d] f32 -> Wt[d][e] bf16 (transpose+convert) ----------
__global__ void wt_kernel(const float* __restrict__ W, unsigned short* __restrict__ Wt) {
  __shared__ float tile[32][33];
  const int e0 = blockIdx.x * 32, d0 = blockIdx.y * 32;
  const int tx = threadIdx.x, ty = threadIdx.y;   // (32,8)
  #pragma unroll
  for (int i = 0; i < 4; ++i)
    tile[ty + i*8][tx] = W[(size_t)(e0 + ty + i*8) * DEC_ + d0 + tx];
  __syncthreads();
  #pragma unroll
  for (int i = 0; i < 4; ++i)
    Wt[(size_t)(d0 + ty + i*8) * ENC_ + e0 + tx] = f2bf(tile[tx][ty + i*8]);
}

// ---------- kernel 3: t[b][d] = dec[b,:] @ U[:,d] (f32), e-split + atomics ----------
__global__ __launch_bounds__(128) void t_kernel(
    const float* __restrict__ dec, const float* __restrict__ U, float* __restrict__ t) {
  __shared__ float decs[B_ * 256];   // 32KB
  const int tid = threadIdx.x;
  const int d  = blockIdx.x * 128 + tid;
  const int e0 = blockIdx.y * 256;
  for (int i = tid; i < B_ * 256 / 4; i += 128) {
    int b  = (i * 4) >> 8;
    int ee = (i * 4) & 255;
    *(float4*)&decs[b * 256 + ee] = *(const float4*)&dec[(size_t)b * DEC_ + e0 + ee];
  }
  __syncthreads();
  float acc[B_] = {};
  for (int e = 0; e < 256; ++e) {
    float u = U[(size_t)(e0 + e) * DEC_ + d];
    #pragma unroll
    for (int b = 0; b < B_; ++b) acc[b] += decs[b * 256 + e] * u;
  }
  #pragma unroll
  for (int b = 0; b < B_; ++b) atomicAdd(&t[b * DEC_ + d], acc[b]);
}

// ---------- kernel 4: fused scores GEMM, 256x256x64, 8-phase pipelined ----------
// 512 threads = 8 waves (2M x 4N), per-wave C = 128x64 (8x4 fragments).
// LDS 128KB: A buf c @ c*32768 (256x64 bf16), B buf c @ 65536 + c*32768.
// Even K-tiles -> buf0, odd -> buf1 (all LDS indices compile-time).
// Swizzle (zero-conflict, verified r2): 16B-slot ^= row&7, applied on the
// pre-swizzled global source (linear global_load_lds dest) and on ds_read.
// Counted vmcnt(2) at phases 4/8 only; stages land in just-dead regions.

#define WAIT_LB    asm volatile("s_waitcnt lgkmcnt(0)\n\ts_barrier" ::: "memory")
#define WAIT_LVB(n) asm volatile("s_waitcnt vmcnt(" #n ") lgkmcnt(0)\n\ts_barrier" ::: "memory")

#define PHASE(CBUF, Q, KK, BLOAD, TAILASM, ...) do {                        \
    bf16x8 af_[4];                                                          \
    const int aA_ = (KK ? aAddr1 : aAddr0) + (CBUF)*32768 + (Q)*16384;      \
    _Pragma("unroll")                                                       \
    for (int mi = 0; mi < 4; ++mi)                                          \
      af_[mi] = *(const bf16x8*)(lds + aA_ + mi*2048);                      \
    if (BLOAD) {                                                            \
      const int bA_ = (KK ? bAddr1 : bAddr0) + (CBUF)*32768;                \
      _Pragma("unroll")                                                     \
      for (int ni = 0; ni < 4; ++ni)                                        \
        bfr[KK][ni] = *(const bf16x8*)(lds + bA_ + ni*2048);                \
    }                                                                       \
    __VA_ARGS__;                                                            \
    asm volatile("s_barrier" ::: "memory");                                 \
    __builtin_amdgcn_s_setprio(1);                                          \
    _Pragma("unroll")                                                       \
    for (int mi = 0; mi < 4; ++mi) {                                        \
      _Pragma("unroll")                                                     \
      for (int ni = 0; ni < 4; ++ni)                                        \
        acc[(Q)*4+mi][ni] = __builtin_amdgcn_mfma_f32_16x16x32_bf16(        \
            af_[mi], bfr[KK][ni], acc[(Q)*4+mi][ni], 0, 0, 0);              \
    }                                                                       \
    __builtin_amdgcn_s_setprio(0);                                          \
    TAILASM;                                                                \
  } while (0)

__global__ __launch_bounds__(512, 2) void scores_kernel(
    const unsigned short* __restrict__ A,     // enc16 [65536][1024]
    const unsigned short* __restrict__ Bt,    // Wt [1024 n][1024 k]
    const float* __restrict__ tb,
    const float* __restrict__ v,
    float* __restrict__ scores)
{
  extern __shared__ char lds[];

  const int tid  = threadIdx.x;
  const int lane = tid & 63;
  const int wid  = tid >> 6;
  const int wr = wid >> 2, wc = wid & 3;        // 2M x 4N wave grid
  const int fr = lane & 15, fq = lane >> 4;

  // XCD swizzle: 1024 blocks (1024%8==0). Each XCD gets 128 consecutive
  // logicals = 32 m-panels x 4 n-blocks; the 4 n-blocks of one m-panel run
  // concurrently on the same XCD -> enc panel L2-shared.
  const int bid = blockIdx.x;
  const int logical = (bid & 7) * 128 + (bid >> 3);
  const int m_blk = logical >> 2, n_blk = logical & 3;
  const int m0 = m_blk << 8;                    // 256 rows
  const int n0 = n_blk << 8;                    // 256 cols
  const int b  = m_blk >> 3;                    // batch (2048 rows / 256)

  // ---- staging source addressing (pre-swizzled global source) ----
  const int srow   = tid >> 3;                          // 0..63
  const int kchunk = (((tid & 7) ^ (srow & 7)) << 3);   // swizzled 16B chunk
  const unsigned short* aP0 = A  + (size_t)(m0       + srow) * ENC_ + kchunk;
  const unsigned short* aP1 = A  + (size_t)(m0 + 64  + srow) * ENC_ + kchunk;
  const unsigned short* aP2 = A  + (size_t)(m0 + 128 + srow) * ENC_ + kchunk;
  const unsigned short* aP3 = A  + (size_t)(m0 + 192 + srow) * ENC_ + kchunk;
  const unsigned short* bP0 = Bt + (size_t)(n0       + srow) * ENC_ + kchunk;
  const unsigned short* bP1 = Bt + (size_t)(n0 + 64  + srow) * ENC_ + kchunk;
  const unsigned short* bP2 = Bt + (size_t)(n0 + 128 + srow) * ENC_ + kchunk;
  const unsigned short* bP3 = Bt + (size_t)(n0 + 192 + srow) * ENC_ + kchunk;
  const int wbase = wid * 1024;                 // wave-uniform LDS dest base

  auto stA = [&](int c, int r, const unsigned short* p) {
    async_copy16(lds + c * 32768 + r * 8192 + wbase, p);
  };
  auto stB = [&](int c, int r, const unsigned short* p) {
    async_copy16(lds + 65536 + c * 32768 + r * 8192 + wbase, p);
  };

  // ---- fragment read addressing (swizzled; all further offsets are imm) ----
  const int sl0 = ((fq)     ^ (fr & 7)) << 4;
  const int sl1 = ((4 + fq) ^ (fr & 7)) << 4;
  const int aAddr0 = (wr * 64 + fr) * 128 + sl0;
  const int aAddr1 = (wr * 64 + fr) * 128 + sl1;
  const int bAddr0 = 65536 + (wc * 64 + fr) * 128 + sl0;
  const int bAddr1 = 65536 + (wc * 64 + fr) * 128 + sl1;

  f32x4 acc[8][4] = {};
  bf16x8 bfr[2][4];

  // ---- prologue: tile0 full -> buf0 (8 rounds), tile1 rounds a0,a1 -> buf1 ----
  stA(0, 0, aP0); stA(0, 1, aP1); stA(0, 2, aP2); stA(0, 3, aP3);
  stB(0, 0, bP0); stB(0, 1, bP1); stB(0, 2, bP2); stB(0, 3, bP3);
  stA(1, 0, aP0 + 64); stA(1, 1, aP1 + 64);
  asm volatile("s_waitcnt vmcnt(2)\n\ts_barrier" ::: "memory");

  #pragma unroll 1
  for (int J = 0; J < 8; ++J) {
    const int ke = J * 128;           // element-k base of tile 2J
    const bool pf = (J < 7);
    // tile 2J from buf0
    PHASE(0, 0, 0, true,  WAIT_LB,
          { stA(1, 2, aP2 + ke + 64); stA(1, 3, aP3 + ke + 64); });
    PHASE(0, 0, 1, true,  WAIT_LB,
          { stB(1, 0, bP0 + ke + 64); stB(1, 1, bP1 + ke + 64); });
    PHASE(0, 1, 0, false, WAIT_LB,
          { stB(1, 2, bP2 + ke + 64); stB(1, 3, bP3 + ke + 64);
            if (pf) { stA(0, 0, aP0 + ke + 128); stA(0, 1, aP1 + ke + 128); } });
    if (pf) { PHASE(0, 1, 1, false, WAIT_LVB(2), {}); }
    else    { PHASE(0, 1, 1, false, WAIT_LVB(0), {}); }
    // tile 2J+1 from buf1
    PHASE(1, 0, 0, true,  WAIT_LB,
          { if (pf) { stA(0, 2, aP2 + ke + 128); stA(0, 3, aP3 + ke + 128); } });
    PHASE(1, 0, 1, true,  WAIT_LB,
          { if (pf) { stB(0, 0, bP0 + ke + 128); stB(0, 1, bP1 + ke + 128); } });
    PHASE(1, 1, 0, false, WAIT_LB,
          { if (pf) { stB(0, 2, bP2 + ke + 128); stB(0, 3, bP3 + ke + 128); } });
    if (pf) { PHASE(1, 1, 1, false, WAIT_LVB(2),
          { stA(1, 0, aP0 + ke + 192); stA(1, 1, aP1 + ke + 192); }); }
    else    { PHASE(1, 1, 1, false, WAIT_LB, {}); }
  }

  // ---- epilogue: v-dot of tanh(acc + t), row-reduce, atomic to scores ----
  asm volatile("s_waitcnt vmcnt(0) lgkmcnt(0)\n\ts_barrier" ::: "memory");
  float* sloc = (float*)lds;
  if (tid < 256) sloc[tid] = 0.f;
  __syncthreads();

  float vv[4], tv[4];
  #pragma unroll
  for (int ni = 0; ni < 4; ++ni) {
    int col = n0 + wc * 64 + ni * 16 + fr;
    vv[ni] = v[col];
    tv[ni] = tb[b * DEC_ + col];
  }
  #pragma unroll
  for (int mi = 0; mi < 8; ++mi) {
    #pragma unroll
    for (int j = 0; j < 4; ++j) {
      float p = 0.f;
      #pragma unroll
      for (int ni = 0; ni < 4; ++ni)
        p += vv[ni] * tanh_fast(acc[mi][ni][j] + tv[ni]);
      p += __shfl_xor(p, 1);
      p += __shfl_xor(p, 2);
      p += __shfl_xor(p, 4);
      p += __shfl_xor(p, 8);
      if (fr == 0)
        atomicAdd(&sloc[(mi >> 2) * 128 + wr * 64 + (mi & 3) * 16 + fq * 4 + j], p);
    }
  }
  __syncthreads();
  if (tid < 256) atomicAdd(&scores[m0 + tid], sloc[tid]);
}

// ---------- kernel 5: masked softmax over S per batch ----------
__global__ __launch_bounds__(256) void softmax_kernel(
    const float* __restrict__ scores, const int* __restrict__ mask,
    float* __restrict__ attn) {
  const int b = blockIdx.x;
  const int tid = threadIdx.x;
  const int lane = tid & 63, w = tid >> 6;
  __shared__ float wred[4];
  float loc[8];
  float mx = -3.0e38f;
  #pragma unroll
  for (int i = 0; i < 8; ++i) {
    int s = tid + i * 256;
    float val = (mask[b * S_ + s] == 0) ? -1e9f : scores[b * S_ + s];
    loc[i] = val;
    mx = fmaxf(mx, val);
  }
  #pragma unroll
  for (int m = 1; m < 64; m <<= 1) mx = fmaxf(mx, __shfl_xor(mx, m));
  if (lane == 0) wred[w] = mx;
  __syncthreads();
  mx = fmaxf(fmaxf(wred[0], wred[1]), fmaxf(wred[2], wred[3]));
  __syncthreads();
  float sum = 0.f;
  #pragma unroll
  for (int i = 0; i < 8; ++i) { loc[i] = __expf(loc[i] - mx); sum += loc[i]; }
  #pragma unroll
  for (int m = 1; m < 64; m <<= 1) sum += __shfl_xor(sum, m);
  if (lane == 0) wred[w] = sum;
  __syncthreads();
  float inv = 1.f / (wred[0] + wred[1] + wred[2] + wred[3]);
  #pragma unroll
  for (int i = 0; i < 8; ++i) attn[b * S_ + tid + i * 256] = loc[i] * inv;
}

// ---------- kernel 6: context[b,e] = sum_s attn[b,s]*enc[b,s,e] ----------
__global__ __launch_bounds__(256) void ctx_kernel(
    const unsigned short* __restrict__ enc16,
    const float* __restrict__ attn,
    float* __restrict__ ctx) {
  const int b  = blockIdx.x;
  const int s0 = blockIdx.y * 128;
  const int tid = threadIdx.x;
  const ushort4* base = reinterpret_cast<const ushort4*>(
      enc16 + ((size_t)b * S_ + s0) * ENC_) + tid;
  float a0 = 0.f, a1 = 0.f, a2 = 0.f, a3 = 0.f;
  for (int s = 0; s < 128; ++s) {
    float a = attn[b * S_ + s0 + s];
    ushort4 ev = base[(size_t)s * 256];
    a0 += a * bf2f(ev.x); a1 += a * bf2f(ev.y);
    a2 += a * bf2f(ev.z); a3 += a * bf2f(ev.w);
  }
  float* c = ctx + (size_t)b * ENC_ + tid * 4;
  atomicAdd(c + 0, a0); atomicAdd(c + 1, a1);
  atomicAdd(c + 2, a2); atomicAdd(c + 3, a3);
}

extern "C" void kernel_launch(void* const* d_in, const int* in_sizes, int n_in,
                              void* d_out, int out_size, void* d_ws, size_t ws_size,
                              hipStream_t stream) {
  const float* enc  = (const float*)d_in[0];
  const float* dec  = (const float*)d_in[1];
  const int*   mask = (const int*)  d_in[2];
  const float* W    = (const float*)d_in[3];
  const float* U    = (const float*)d_in[4];
  const float* v    = (const float*)d_in[5];

  float* out  = (float*)d_out;
  float* ctx  = out;
  float* attn = out + B_ * ENC_;

  char* ws = (char*)d_ws;
  unsigned short* enc16 = (unsigned short*)ws;                                    // 128MB
  unsigned short* Wt    = (unsigned short*)(ws + (size_t)M_ * ENC_ * 2);          // 2MB
  float* t_buf  = (float*)(ws + (size_t)M_ * ENC_ * 2 + (size_t)ENC_ * DEC_ * 2); // 128KB
  float* scores = (float*)((char*)t_buf + (size_t)B_ * DEC_ * 4);                 // 256KB

  (void)hipFuncSetAttribute((const void*)scores_kernel,
                            hipFuncAttributeMaxDynamicSharedMemorySize, 131072);

  hipMemsetAsync(scores, 0, (size_t)M_ * 4, stream);
  hipMemsetAsync(t_buf, 0, (size_t)B_ * DEC_ * 4, stream);
  hipMemsetAsync(ctx, 0, (size_t)B_ * ENC_ * 4, stream);

  cvt_enc_kernel<<<8192, 256, 0, stream>>>(
      (const float4*)enc, (ushort4*)enc16, M_ * ENC_ / 4);
  wt_kernel<<<dim3(ENC_ / 32, DEC_ / 32), dim3(32, 8), 0, stream>>>(W, Wt);
  t_kernel<<<dim3(DEC_ / 128, 4), 128, 0, stream>>>(dec, U, t_buf);

  scores_kernel<<<1024, 512, 131072, stream>>>(enc16, Wt, t_buf, v, scores);

  softmax_kernel<<<B_, 256, 0, stream>>>(scores, mask, attn);

  ctx_kernel<<<dim3(B_, S_ / 128), 256, 0, stream>>>(enc16, attn, ctx);
}

// Round 4
// 327.050 us; speedup vs baseline: 1.3158x; 1.0213x over previous
//
#include <hip/hip_runtime.h>
#include <hip/hip_bf16.h>
#include <stdint.h>

// Problem dims (fixed)
#define B_    32
#define S_    2048
#define ENC_  1024
#define DEC_  1024
#define M_    (B_*S_)   // 65536

typedef __attribute__((ext_vector_type(8))) short bf16x8;
typedef __attribute__((ext_vector_type(4))) float f32x4;

__device__ __forceinline__ unsigned short f2bf(float f) {
  unsigned u = __builtin_bit_cast(unsigned, f);
  u += 0x7FFFu + ((u >> 16) & 1u);            // RNE
  return (unsigned short)(u >> 16);
}
__device__ __forceinline__ float bf2f(unsigned short u) {
  unsigned x = ((unsigned)u) << 16;
  return __builtin_bit_cast(float, x);
}
__device__ __forceinline__ void async_copy16(void* lds_dst, const void* g_src) {
  __builtin_amdgcn_global_load_lds(
      (const __attribute__((address_space(1))) void*)g_src,
      (__attribute__((address_space(3))) void*)lds_dst, 16, 0, 0);
}
__device__ __forceinline__ float tanh_fast(float x) {
  return 1.f - 2.f / (__expf(2.f * x) + 1.f);
}

// ---------- kernel 1: enc f32 -> bf16 ----------
__global__ __launch_bounds__(256) void cvt_enc_kernel(
    const float4* __restrict__ in, ushort4* __restrict__ out, int n4) {
  int idx = blockIdx.x * blockDim.x + threadIdx.x;
  int stride = gridDim.x * blockDim.x;
  for (int i = idx; i < n4; i += stride) {
    float4 f = in[i];
    ushort4 o;
    o.x = f2bf(f.x); o.y = f2bf(f.y); o.z = f2bf(f.z); o.w = f2bf(f.w);
    out[i] = o;
  }
}

// ---------- kernel 2: W[e][d] f32 -> Wt[d][e] bf16 (transpose+convert) ----------
__global__ void wt_kernel(const float* __restrict__ W, unsigned short* __restrict__ Wt) {
  __shared__ float tile[32][33];
  const int e0 = blockIdx.x * 32, d0 = blockIdx.y * 32;
  const int tx = threadIdx.x, ty = threadIdx.y;   // (32,8)
  #pragma unroll
  for (int i = 0; i < 4; ++i)
    tile[ty + i*8][tx] = W[(size_t)(e0 + ty + i*8) * DEC_ + d0 + tx];
  __syncthreads();
  #pragma unroll
  for (int i = 0; i < 4; ++i)
    Wt[(size_t)(d0 + ty + i*8) * ENC_ + e0 + tx] = f2bf(tile[tx][ty + i*8]);
}

// ---------- kernel 3: t[b][d] = dec[b,:] @ U[:,d] (f32), e-split + atomics ----------
__global__ __launch_bounds__(128) void t_kernel(
    const float* __restrict__ dec, const float* __restrict__ U, float* __restrict__ t) {
  __shared__ float decs[B_ * 256];   // 32KB
  const int tid = threadIdx.x;
  const int d  = blockIdx.x * 128 + tid;
  const int e0 = blockIdx.y * 256;
  for (int i = tid; i < B_ * 256 / 4; i += 128) {
    int b  = (i * 4) >> 8;
    int ee = (i * 4) & 255;
    *(float4*)&decs[b * 256 + ee] = *(const float4*)&dec[(size_t)b * DEC_ + e0 + ee];
  }
  __syncthreads();
  float acc[B_] = {};
  for (int e = 0; e < 256; ++e) {
    float u = U[(size_t)(e0 + e) * DEC_ + d];
    #pragma unroll
    for (int b = 0; b < B_; ++b) acc[b] += decs[b * 256 + e] * u;
  }
  #pragma unroll
  for (int b = 0; b < B_; ++b) atomicAdd(&t[b * DEC_ + d], acc[b]);
}

// ---------- kernel 4: fused scores GEMM, 256x256x64, 8-phase (m201-template) ----------
// 512 threads = 8 waves (2M x 4N), per-wave C = 128x64 (2Q x 4 fragments).
// LDS 128KB: A buf c @ c*32768 (256x64 bf16), B buf c @ 65536 + c*32768.
// Even K-tiles -> buf0, odd -> buf1 (compile-time LDS indices).
// T2 swizzle (zero-conflict): 16B-slot ^= row&7 via pre-swizzled global src
// (linear global_load_lds dest) + swizzled ds_read.
// 2 stages/phase; counted vmcnt(4) at phases 4/8 only (12 in flight -> 8 drained).
// sched_barrier(0) fences each MFMA cluster so it can't migrate across phases.

#define WT_L  asm volatile("s_waitcnt lgkmcnt(0)" ::: "memory")
#define WT_V4 asm volatile("s_waitcnt vmcnt(4) lgkmcnt(0)" ::: "memory")
#define WT_V0 asm volatile("s_waitcnt vmcnt(0) lgkmcnt(0)" ::: "memory")

#define PHASE(CBUF, Q, KK, BLOAD, TAILWAIT, ...) do {                       \
    bf16x8 af_[4];                                                          \
    const int aA_ = (KK ? aAddr1 : aAddr0) + (CBUF)*32768 + (Q)*16384;      \
    _Pragma("unroll")                                                       \
    for (int mi = 0; mi < 4; ++mi)                                          \
      af_[mi] = *(const bf16x8*)(lds + aA_ + mi*2048);                      \
    if (BLOAD) {                                                            \
      const int bA_ = (KK ? bAddr1 : bAddr0) + (CBUF)*32768;                \
      _Pragma("unroll")                                                     \
      for (int ni = 0; ni < 4; ++ni)                                        \
        bfr[KK][ni] = *(const bf16x8*)(lds + bA_ + ni*2048);                \
    }                                                                       \
    __VA_ARGS__;                                                            \
    __builtin_amdgcn_s_barrier();                                           \
    __builtin_amdgcn_sched_barrier(0);                                      \
    __builtin_amdgcn_s_setprio(1);                                          \
    _Pragma("unroll")                                                       \
    for (int mi = 0; mi < 4; ++mi) {                                        \
      _Pragma("unroll")                                                     \
      for (int ni = 0; ni < 4; ++ni)                                        \
        acc[(Q)*4+mi][ni] = __builtin_amdgcn_mfma_f32_16x16x32_bf16(        \
            af_[mi], bfr[KK][ni], acc[(Q)*4+mi][ni], 0, 0, 0);              \
    }                                                                       \
    __builtin_amdgcn_s_setprio(0);                                          \
    __builtin_amdgcn_sched_barrier(0);                                      \
    TAILWAIT;                                                               \
    __builtin_amdgcn_s_barrier();                                           \
  } while (0)

__global__ __launch_bounds__(512, 2) void scores_kernel(
    const unsigned short* __restrict__ A,     // enc16 [65536][1024]
    const unsigned short* __restrict__ Bt,    // Wt [1024 n][1024 k]
    const float* __restrict__ tb,
    const float* __restrict__ v,
    float* __restrict__ scores)
{
  extern __shared__ char lds[];

  const int tid  = threadIdx.x;
  const int lane = tid & 63;
  const int wid  = tid >> 6;
  const int wr = wid >> 2, wc = wid & 3;        // 2M x 4N wave grid
  const int fr = lane & 15, fq = lane >> 4;

  // XCD swizzle: 1024 blocks, bijective (1024%8==0). 4 n-blocks of one
  // m-panel run concurrently on one XCD -> enc panel L2-shared.
  const int bid = blockIdx.x;
  const int logical = (bid & 7) * 128 + (bid >> 3);
  const int m_blk = logical >> 2, n_blk = logical & 3;
  const int m0 = m_blk << 8;                    // 256 rows
  const int n0 = n_blk << 8;                    // 256 cols
  const int b  = m_blk >> 3;                    // batch (2048 rows / 256)

  // ---- staging source addressing (pre-swizzled global source) ----
  const int srow   = tid >> 3;                          // 0..63
  const int kchunk = (((tid & 7) ^ (srow & 7)) << 3);   // swizzled 16B chunk
  const unsigned short* aP0 = A  + (size_t)(m0       + srow) * ENC_ + kchunk;
  const unsigned short* aP1 = A  + (size_t)(m0 + 64  + srow) * ENC_ + kchunk;
  const unsigned short* aP2 = A  + (size_t)(m0 + 128 + srow) * ENC_ + kchunk;
  const unsigned short* aP3 = A  + (size_t)(m0 + 192 + srow) * ENC_ + kchunk;
  const unsigned short* bP0 = Bt + (size_t)(n0       + srow) * ENC_ + kchunk;
  const unsigned short* bP1 = Bt + (size_t)(n0 + 64  + srow) * ENC_ + kchunk;
  const unsigned short* bP2 = Bt + (size_t)(n0 + 128 + srow) * ENC_ + kchunk;
  const unsigned short* bP3 = Bt + (size_t)(n0 + 192 + srow) * ENC_ + kchunk;
  const int wbase = wid * 1024;                 // wave-uniform LDS dest base

  auto stA = [&](int c, int r, const unsigned short* p) {
    async_copy16(lds + c * 32768 + r * 8192 + wbase, p);
  };
  auto stB = [&](int c, int r, const unsigned short* p) {
    async_copy16(lds + 65536 + c * 32768 + r * 8192 + wbase, p);
  };

  // ---- fragment read addressing (swizzled; further offsets compile-time) ----
  const int sl0 = ((fq)     ^ (fr & 7)) << 4;
  const int sl1 = ((4 + fq) ^ (fr & 7)) << 4;
  const int aAddr0 = (wr * 64 + fr) * 128 + sl0;
  const int aAddr1 = (wr * 64 + fr) * 128 + sl1;
  const int bAddr0 = 65536 + (wc * 64 + fr) * 128 + sl0;
  const int bAddr1 = 65536 + (wc * 64 + fr) * 128 + sl1;

  f32x4 acc[8][4] = {};
  bf16x8 bfr[2][4];

  // ---- prologue: tile0 full -> buf0; tile1 A0,A1,B0,B1 -> buf1 ----
  stA(0, 0, aP0); stA(0, 1, aP1); stA(0, 2, aP2); stA(0, 3, aP3);
  stB(0, 0, bP0); stB(0, 1, bP1); stB(0, 2, bP2); stB(0, 3, bP3);
  stA(1, 0, aP0 + 64); stA(1, 1, aP1 + 64);
  stB(1, 0, bP0 + 64); stB(1, 1, bP1 + 64);
  asm volatile("s_waitcnt vmcnt(4)" ::: "memory");
  __builtin_amdgcn_s_barrier();

  // ---- main loop: iterations 0..6 (pf), 7 peeled ----
  #pragma unroll 1
  for (int J = 0; J < 7; ++J) {
    const int ke = J * 128;
    PHASE(0,0,0,true,  WT_L,  { stB(1,2,bP2+ke+64);  stB(1,3,bP3+ke+64);  });
    PHASE(0,0,1,true,  WT_L,  { stA(1,2,aP2+ke+64);  stA(1,3,aP3+ke+64);  });
    PHASE(0,1,0,false, WT_L,  { stA(0,0,aP0+ke+128); stA(0,1,aP1+ke+128); });
    PHASE(0,1,1,false, WT_V4, { stB(0,0,bP0+ke+128); stB(0,1,bP1+ke+128); });
    PHASE(1,0,0,true,  WT_L,  { stB(0,2,bP2+ke+128); stB(0,3,bP3+ke+128); });
    PHASE(1,0,1,true,  WT_L,  { stA(0,2,aP2+ke+128); stA(0,3,aP3+ke+128); });
    PHASE(1,1,0,false, WT_L,  { stA(1,0,aP0+ke+192); stA(1,1,aP1+ke+192); });
    PHASE(1,1,1,false, WT_V4, { stB(1,0,bP0+ke+192); stB(1,1,bP1+ke+192); });
  }
  {
    const int ke = 896;
    PHASE(0,0,0,true,  WT_L,  { stB(1,2,bP2+ke+64); stB(1,3,bP3+ke+64); });
    PHASE(0,0,1,true,  WT_L,  { stA(1,2,aP2+ke+64); stA(1,3,aP3+ke+64); });
    PHASE(0,1,0,false, WT_L,  {});
    PHASE(0,1,1,false, WT_V0, {});
    PHASE(1,0,0,true,  WT_L,  {});
    PHASE(1,0,1,true,  WT_L,  {});
    PHASE(1,1,0,false, WT_L,  {});
    PHASE(1,1,1,false, WT_V0, {});
  }

  // ---- epilogue: v-dot of tanh(acc + t), row-reduce, atomic to scores ----
  asm volatile("s_waitcnt vmcnt(0) lgkmcnt(0)" ::: "memory");
  __builtin_amdgcn_s_barrier();
  float* sloc = (float*)lds;
  if (tid < 256) sloc[tid] = 0.f;
  __syncthreads();

  float vv[4], tv[4];
  #pragma unroll
  for (int ni = 0; ni < 4; ++ni) {
    int col = n0 + wc * 64 + ni * 16 + fr;
    vv[ni] = v[col];
    tv[ni] = tb[b * DEC_ + col];
  }
  #pragma unroll
  for (int mi = 0; mi < 8; ++mi) {
    #pragma unroll
    for (int j = 0; j < 4; ++j) {
      float p = 0.f;
      #pragma unroll
      for (int ni = 0; ni < 4; ++ni)
        p += vv[ni] * tanh_fast(acc[mi][ni][j] + tv[ni]);
      p += __shfl_xor(p, 1);
      p += __shfl_xor(p, 2);
      p += __shfl_xor(p, 4);
      p += __shfl_xor(p, 8);
      if (fr == 0)
        atomicAdd(&sloc[(mi >> 2) * 128 + wr * 64 + (mi & 3) * 16 + fq * 4 + j], p);
    }
  }
  __syncthreads();
  if (tid < 256) atomicAdd(&scores[m0 + tid], sloc[tid]);
}

// ---------- kernel 5: masked softmax over S per batch ----------
__global__ __launch_bounds__(256) void softmax_kernel(
    const float* __restrict__ scores, const int* __restrict__ mask,
    float* __restrict__ attn) {
  const int b = blockIdx.x;
  const int tid = threadIdx.x;
  const int lane = tid & 63, w = tid >> 6;
  __shared__ float wred[4];
  float loc[8];
  float mx = -3.0e38f;
  #pragma unroll
  for (int i = 0; i < 8; ++i) {
    int s = tid + i * 256;
    float val = (mask[b * S_ + s] == 0) ? -1e9f : scores[b * S_ + s];
    loc[i] = val;
    mx = fmaxf(mx, val);
  }
  #pragma unroll
  for (int m = 1; m < 64; m <<= 1) mx = fmaxf(mx, __shfl_xor(mx, m));
  if (lane == 0) wred[w] = mx;
  __syncthreads();
  mx = fmaxf(fmaxf(wred[0], wred[1]), fmaxf(wred[2], wred[3]));
  __syncthreads();
  float sum = 0.f;
  #pragma unroll
  for (int i = 0; i < 8; ++i) { loc[i] = __expf(loc[i] - mx); sum += loc[i]; }
  #pragma unroll
  for (int m = 1; m < 64; m <<= 1) sum += __shfl_xor(sum, m);
  if (lane == 0) wred[w] = sum;
  __syncthreads();
  float inv = 1.f / (wred[0] + wred[1] + wred[2] + wred[3]);
  #pragma unroll
  for (int i = 0; i < 8; ++i) attn[b * S_ + tid + i * 256] = loc[i] * inv;
}

// ---------- kernel 6: context[b,e] = sum_s attn[b,s]*enc[b,s,e] ----------
__global__ __launch_bounds__(256) void ctx_kernel(
    const unsigned short* __restrict__ enc16,
    const float* __restrict__ attn,
    float* __restrict__ ctx) {
  const int b  = blockIdx.x;
  const int s0 = blockIdx.y * 128;
  const int tid = threadIdx.x;
  const ushort4* base = reinterpret_cast<const ushort4*>(
      enc16 + ((size_t)b * S_ + s0) * ENC_) + tid;
  float a0 = 0.f, a1 = 0.f, a2 = 0.f, a3 = 0.f;
  for (int s = 0; s < 128; ++s) {
    float a = attn[b * S_ + s0 + s];
    ushort4 ev = base[(size_t)s * 256];
    a0 += a * bf2f(ev.x); a1 += a * bf2f(ev.y);
    a2 += a * bf2f(ev.z); a3 += a * bf2f(ev.w);
  }
  float* c = ctx + (size_t)b * ENC_ + tid * 4;
  atomicAdd(c + 0, a0); atomicAdd(c + 1, a1);
  atomicAdd(c + 2, a2); atomicAdd(c + 3, a3);
}

extern "C" void kernel_launch(void* const* d_in, const int* in_sizes, int n_in,
                              void* d_out, int out_size, void* d_ws, size_t ws_size,
                              hipStream_t stream) {
  const float* enc  = (const float*)d_in[0];
  const float* dec  = (const float*)d_in[1];
  const int*   mask = (const int*)  d_in[2];
  const float* W    = (const float*)d_in[3];
  const float* U    = (const float*)d_in[4];
  const float* v    = (const float*)d_in[5];

  float* out  = (float*)d_out;
  float* ctx  = out;
  float* attn = out + B_ * ENC_;

  char* ws = (char*)d_ws;
  unsigned short* enc16 = (unsigned short*)ws;                                    // 128MB
  unsigned short* Wt    = (unsigned short*)(ws + (size_t)M_ * ENC_ * 2);          // 2MB
  float* t_buf  = (float*)(ws + (size_t)M_ * ENC_ * 2 + (size_t)ENC_ * DEC_ * 2); // 128KB
  float* scores = (float*)((char*)t_buf + (size_t)B_ * DEC_ * 4);                 // 256KB

  (void)hipFuncSetAttribute((const void*)scores_kernel,
                            hipFuncAttributeMaxDynamicSharedMemorySize, 131072);

  hipMemsetAsync(scores, 0, (size_t)M_ * 4, stream);
  hipMemsetAsync(t_buf, 0, (size_t)B_ * DEC_ * 4, stream);
  hipMemsetAsync(ctx, 0, (size_t)B_ * ENC_ * 4, stream);

  cvt_enc_kernel<<<8192, 256, 0, stream>>>(
      (const float4*)enc, (ushort4*)enc16, M_ * ENC_ / 4);
  wt_kernel<<<dim3(ENC_ / 32, DEC_ / 32), dim3(32, 8), 0, stream>>>(W, Wt);
  t_kernel<<<dim3(DEC_ / 128, 4), 128, 0, stream>>>(dec, U, t_buf);

  scores_kernel<<<1024, 512, 131072, stream>>>(enc16, Wt, t_buf, v, scores);

  softmax_kernel<<<B_, 256, 0, stream>>>(scores, mask, attn);

  ctx_kernel<<<dim3(B_, S_ / 128), 256, 0, stream>>>(enc16, attn, ctx);
}

// Round 5
// 310.373 us; speedup vs baseline: 1.3865x; 1.0537x over previous
//
#include <hip/hip_runtime.h>
#include <hip/hip_bf16.h>
#include <stdint.h>

// Problem dims (fixed)
#define B_    32
#define S_    2048
#define ENC_  1024
#define DEC_  1024
#define M_    (B_*S_)   // 65536

typedef __attribute__((ext_vector_type(8))) short bf16x8;
typedef __attribute__((ext_vector_type(4))) float f32x4;

__device__ __forceinline__ unsigned short f2bf(float f) {
  unsigned u = __builtin_bit_cast(unsigned, f);
  u += 0x7FFFu + ((u >> 16) & 1u);            // RNE
  return (unsigned short)(u >> 16);
}
__device__ __forceinline__ float bf2f(unsigned short u) {
  unsigned x = ((unsigned)u) << 16;
  return __builtin_bit_cast(float, x);
}
__device__ __forceinline__ void async_copy16(void* lds_dst, const void* g_src) {
  __builtin_amdgcn_global_load_lds(
      (const __attribute__((address_space(1))) void*)g_src,
      (__attribute__((address_space(3))) void*)lds_dst, 16, 0, 0);
}
__device__ __forceinline__ float tanh_fast(float x) {
  return 1.f - 2.f / (__expf(2.f * x) + 1.f);
}

// ---------- kernel 1: prep = Wt transpose/convert + t = dec@U + zero buffers ----------
__global__ __launch_bounds__(256) void prep_kernel(
    const float* __restrict__ W, const float* __restrict__ dec,
    const float* __restrict__ U, unsigned short* __restrict__ Wt,
    float* __restrict__ t_buf, float* __restrict__ scoresZ,
    float* __restrict__ ctxZ) {
  __shared__ float smem[32 * 33];
  const int blk = blockIdx.x, tid = threadIdx.x;
  if (blk < 1024) {
    // W[e][d] f32 -> Wt[d][e] bf16
    const int e0 = (blk & 31) * 32, d0 = (blk >> 5) * 32;
    const int tx = tid & 31, ty = tid >> 5;   // 32 x 8
    #pragma unroll
    for (int i = 0; i < 4; ++i)
      smem[(ty + i*8)*33 + tx] = W[(size_t)(e0 + ty + i*8) * DEC_ + d0 + tx];
    __syncthreads();
    #pragma unroll
    for (int i = 0; i < 4; ++i)
      Wt[(size_t)(d0 + ty + i*8) * ENC_ + e0 + tx] = f2bf(smem[tx*33 + ty + i*8]);
  } else if (blk < 1280) {
    // t[b][d] = dec[b,:] . U[:,d]  (atomic-free: 2 e-halves reduced in LDS)
    const int q = blk - 1024;
    const int dblk = q & 7, b = q >> 3;
    const int d = dblk * 128 + (tid & 127);
    const int h = tid >> 7;
    float acc = 0.f;
    const float* dv = dec + b * DEC_ + h * 512;
    const float* Uc = U + (size_t)(h * 512) * DEC_ + d;
    for (int e = 0; e < 512; ++e) acc += dv[e] * Uc[(size_t)e * DEC_];
    smem[tid] = acc;
    __syncthreads();
    if (tid < 128) t_buf[b * DEC_ + d] = smem[tid] + smem[tid + 128];
  } else {
    // zero scores (65536 f) and ctx (32768 f)
    const int q = blk - 1280;   // 32 blocks
    float4 z = {0.f, 0.f, 0.f, 0.f};
    for (int i = tid; i < 512; i += 256) ((float4*)scoresZ)[q * 512 + i] = z;
    for (int i = tid; i < 256; i += 256) ((float4*)ctxZ)[q * 256 + i] = z;
  }
}

// ---------- kernel 2: fused scores GEMM, 256x256x64, 8-phase ----------
// A-side: reg-staged f32 enc -> f2bf -> swizzled ds_write_b128 (fuses the cvt
// pass); writer blocks (n_blk==0) also store bf16 out to enc16 for ctx.
// B-side: global_load_lds with pre-swizzled source (unchanged, zero-conflict).
// Correctness of B-load retirement: each phase's ds_write has a register dep
// on f32 loads issued AFTER the B-glds -> compiler auto-vmcnt retires them
// (FIFO) at least one full tile before the B data is read; per-phase
// lgkmcnt(0)+barrier publishes ds_writes. No manual vmcnt in the main loop.

#define WT_L asm volatile("s_waitcnt lgkmcnt(0)" ::: "memory")

#define STB4(SC, KN) do {                                                   \
    async_copy16(lds + 65536 + (SC)*32768 + 0*8192 + wbase, bP0 + (KN));    \
    async_copy16(lds + 65536 + (SC)*32768 + 1*8192 + wbase, bP1 + (KN));    \
    async_copy16(lds + 65536 + (SC)*32768 + 2*8192 + wbase, bP2 + (KN));    \
    async_copy16(lds + 65536 + (SC)*32768 + 3*8192 + wbase, bP3 + (KN));    \
  } while (0)

#define LDA(P0, P1, WIDX, KN) do {                                          \
    P0 = *(const float4*)(aF + (size_t)(WIDX)*65536 + (KN));                \
    P1 = *(const float4*)(aF + (size_t)(WIDX)*65536 + (KN) + 4);            \
  } while (0)

#define WRA(BUF, WIDX, KN, P0, P1) do {                                     \
    bf16x8 t_;                                                              \
    t_[0]=(short)f2bf(P0.x); t_[1]=(short)f2bf(P0.y);                       \
    t_[2]=(short)f2bf(P0.z); t_[3]=(short)f2bf(P0.w);                       \
    t_[4]=(short)f2bf(P1.x); t_[5]=(short)f2bf(P1.y);                       \
    t_[6]=(short)f2bf(P1.z); t_[7]=(short)f2bf(P1.w);                       \
    *(bf16x8*)(lds + (BUF)*32768 + (WIDX)*8192 + awBase) = t_;              \
    if (writer) *(bf16x8*)(aOut + (size_t)(WIDX)*65536 + (KN)) = t_;        \
  } while (0)

// BM: 0 = read B + cache in bfr, 1 = read B transient, 2 = reuse bfr
#define PHASE(RC, Q, KK, BM, ...) do {                                      \
    bf16x8 af_[4], bb_[4];                                                  \
    { const int aA_ = (KK ? aAddr1 : aAddr0) + (RC)*32768 + (Q)*16384;      \
      _Pragma("unroll")                                                     \
      for (int mi = 0; mi < 4; ++mi)                                        \
        af_[mi] = *(const bf16x8*)(lds + aA_ + mi*2048); }                  \
    if (BM != 2) {                                                          \
      const int bA_ = (KK ? bAddr1 : bAddr0) + (RC)*32768;                  \
      _Pragma("unroll")                                                     \
      for (int ni = 0; ni < 4; ++ni)                                        \
        bb_[ni] = *(const bf16x8*)(lds + bA_ + ni*2048);                    \
      if (BM == 0) { _Pragma("unroll")                                      \
        for (int ni = 0; ni < 4; ++ni) bfr[ni] = bb_[ni]; }                 \
    } else { _Pragma("unroll")                                              \
      for (int ni = 0; ni < 4; ++ni) bb_[ni] = bfr[ni]; }                   \
    __VA_ARGS__;                                                            \
    __builtin_amdgcn_s_barrier();                                           \
    __builtin_amdgcn_sched_barrier(0);                                      \
    __builtin_amdgcn_s_setprio(1);                                          \
    _Pragma("unroll")                                                       \
    for (int mi = 0; mi < 4; ++mi) {                                        \
      _Pragma("unroll")                                                     \
      for (int ni = 0; ni < 4; ++ni)                                        \
        acc[(Q)*4+mi][ni] = __builtin_amdgcn_mfma_f32_16x16x32_bf16(        \
            af_[mi], bb_[ni], acc[(Q)*4+mi][ni], 0, 0, 0);                  \
    }                                                                       \
    __builtin_amdgcn_s_setprio(0);                                          \
    __builtin_amdgcn_sched_barrier(0);                                      \
    WT_L;                                                                   \
    __builtin_amdgcn_s_barrier();                                           \
  } while (0)

// One K64-tile: read buf RC; stage tile t+1 (k base KN) into SC.
// WRA3 of THIS tile's staging lands at the NEXT tile's ph0 (rows 192-255,
// read only at Q1 phases -> published by ph0's lgkm+barrier).
#define TILE(RC, SC, KN, STG) do {                                          \
    PHASE(RC,0,0,0, { WRA(RC,3,(KN)-64, la2,la3);                           \
                      if (STG) { STB4(SC,(KN)); LDA(la0,la1, 0,(KN)); } }); \
    PHASE(RC,0,1,1, { if (STG) { LDA(la2,la3, 1,(KN));                      \
                                 WRA(SC,0,(KN), la0,la1); } });             \
    PHASE(RC,1,0,2, { if (STG) { LDA(la0,la1, 2,(KN));                      \
                                 WRA(SC,1,(KN), la2,la3); } });             \
    PHASE(RC,1,1,1, { if (STG) { LDA(la2,la3, 3,(KN));                      \
                                 WRA(SC,2,(KN), la0,la1); } });             \
  } while (0)

__global__ __launch_bounds__(512, 2) void scores_kernel(
    const float* __restrict__ A32,            // enc f32 [65536][1024]
    const unsigned short* __restrict__ Bt,    // Wt bf16 [1024 n][1024 k]
    const float* __restrict__ tb,
    const float* __restrict__ v,
    float* __restrict__ scores,
    unsigned short* __restrict__ enc16out)    // bf16 enc written by n_blk==0
{
  extern __shared__ char lds[];

  const int tid  = threadIdx.x;
  const int lane = tid & 63;
  const int wid  = tid >> 6;
  const int wr = wid >> 2, wc = wid & 3;        // 2M x 4N wave grid
  const int fr = lane & 15, fq = lane >> 4;

  // XCD swizzle (bijective, 1024 % 8 == 0)
  const int bid = blockIdx.x;
  const int logical = (bid & 7) * 128 + (bid >> 3);
  const int m_blk = logical >> 2, n_blk = logical & 3;
  const int m0 = m_blk << 8;
  const int n0 = n_blk << 8;
  const int b  = m_blk >> 3;
  const bool writer = (n_blk == 0);

  // ---- staging addressing ----
  const int srow = tid >> 3;                            // 0..63
  // B source pre-swizzled (global_load_lds dest is linear)
  const int kchunk = (((tid & 7) ^ (srow & 7)) << 3);
  const unsigned short* bP0 = Bt + (size_t)(n0       + srow) * ENC_ + kchunk;
  const unsigned short* bP1 = Bt + (size_t)(n0 + 64  + srow) * ENC_ + kchunk;
  const unsigned short* bP2 = Bt + (size_t)(n0 + 128 + srow) * ENC_ + kchunk;
  const unsigned short* bP3 = Bt + (size_t)(n0 + 192 + srow) * ENC_ + kchunk;
  const int wbase = wid * 1024;
  // A source natural f32; ds_write dest carries the swizzle
  const float* aF = A32 + (size_t)(m0 + srow) * ENC_ + (tid & 7) * 8;
  unsigned short* aOut = enc16out + (size_t)(m0 + srow) * ENC_ + (tid & 7) * 8;
  const int awBase = srow * 128 + (((tid & 7) ^ (srow & 7)) << 4);

  // ---- fragment read addressing (swizzled) ----
  const int sl0 = ((fq)     ^ (fr & 7)) << 4;
  const int sl1 = ((4 + fq) ^ (fr & 7)) << 4;
  const int aAddr0 = (wr * 64 + fr) * 128 + sl0;
  const int aAddr1 = (wr * 64 + fr) * 128 + sl1;
  const int bAddr0 = 65536 + (wc * 64 + fr) * 128 + sl0;
  const int bAddr1 = 65536 + (wc * 64 + fr) * 128 + sl1;

  f32x4 acc[8][4] = {};
  bf16x8 bfr[4];
  float4 la0, la1, la2, la3;

  // ---- prologue: stage tile0 fully into buf0 (w3 pair left live) ----
  STB4(0, 0);
  LDA(la0, la1, 0, 0); LDA(la2, la3, 1, 0);
  WRA(0, 0, 0, la0, la1);
  LDA(la0, la1, 2, 0);
  WRA(0, 1, 0, la2, la3);
  LDA(la2, la3, 3, 0);
  WRA(0, 2, 0, la0, la1);
  asm volatile("s_waitcnt vmcnt(0) lgkmcnt(0)" ::: "memory");
  __builtin_amdgcn_s_barrier();

  // ---- main loop: tiles 0..13, then 14 (stage 15), then 15 (no stage) ----
  #pragma unroll 1
  for (int J = 0; J < 7; ++J) {
    const int k1 = J * 128 + 64, k2 = J * 128 + 128;
    TILE(0, 1, k1, 1);
    TILE(1, 0, k2, 1);
  }
  TILE(0, 1, 960, 1);
  TILE(1, 0, 1024, 0);

  // ---- epilogue: v-dot of tanh(acc + t), row-reduce, atomic to scores ----
  asm volatile("s_waitcnt vmcnt(0) lgkmcnt(0)" ::: "memory");
  __builtin_amdgcn_s_barrier();
  float* sloc = (float*)lds;
  if (tid < 256) sloc[tid] = 0.f;
  __syncthreads();

  float vv[4], tv[4];
  #pragma unroll
  for (int ni = 0; ni < 4; ++ni) {
    int col = n0 + wc * 64 + ni * 16 + fr;
    vv[ni] = v[col];
    tv[ni] = tb[b * DEC_ + col];
  }
  #pragma unroll
  for (int mi = 0; mi < 8; ++mi) {
    #pragma unroll
    for (int j = 0; j < 4; ++j) {
      float p = 0.f;
      #pragma unroll
      for (int ni = 0; ni < 4; ++ni)
        p += vv[ni] * tanh_fast(acc[mi][ni][j] + tv[ni]);
      p += __shfl_xor(p, 1);
      p += __shfl_xor(p, 2);
      p += __shfl_xor(p, 4);
      p += __shfl_xor(p, 8);
      if (fr == 0)
        atomicAdd(&sloc[(mi >> 2) * 128 + wr * 64 + (mi & 3) * 16 + fq * 4 + j], p);
    }
  }
  __syncthreads();
  if (tid < 256) atomicAdd(&scores[m0 + tid], sloc[tid]);
}

// ---------- kernel 3: masked softmax over S per batch ----------
__global__ __launch_bounds__(256) void softmax_kernel(
    const float* __restrict__ scores, const int* __restrict__ mask,
    float* __restrict__ attn) {
  const int b = blockIdx.x;
  const int tid = threadIdx.x;
  const int lane = tid & 63, w = tid >> 6;
  __shared__ float wred[4];
  float loc[8];
  float mx = -3.0e38f;
  #pragma unroll
  for (int i = 0; i < 8; ++i) {
    int s = tid + i * 256;
    float val = (mask[b * S_ + s] == 0) ? -1e9f : scores[b * S_ + s];
    loc[i] = val;
    mx = fmaxf(mx, val);
  }
  #pragma unroll
  for (int m = 1; m < 64; m <<= 1) mx = fmaxf(mx, __shfl_xor(mx, m));
  if (lane == 0) wred[w] = mx;
  __syncthreads();
  mx = fmaxf(fmaxf(wred[0], wred[1]), fmaxf(wred[2], wred[3]));
  __syncthreads();
  float sum = 0.f;
  #pragma unroll
  for (int i = 0; i < 8; ++i) { loc[i] = __expf(loc[i] - mx); sum += loc[i]; }
  #pragma unroll
  for (int m = 1; m < 64; m <<= 1) sum += __shfl_xor(sum, m);
  if (lane == 0) wred[w] = sum;
  __syncthreads();
  float inv = 1.f / (wred[0] + wred[1] + wred[2] + wred[3]);
  #pragma unroll
  for (int i = 0; i < 8; ++i) attn[b * S_ + tid + i * 256] = loc[i] * inv;
}

// ---------- kernel 4: context[b,e] = sum_s attn[b,s]*enc16[b,s,e] ----------
__global__ __launch_bounds__(256) void ctx_kernel(
    const unsigned short* __restrict__ enc16,
    const float* __restrict__ attn,
    float* __restrict__ ctx) {
  const int b  = blockIdx.x;
  const int s0 = blockIdx.y * 256;
  const int tid = threadIdx.x;
  const ushort4* base = reinterpret_cast<const ushort4*>(
      enc16 + ((size_t)b * S_ + s0) * ENC_) + tid;
  float a0 = 0.f, a1 = 0.f, a2 = 0.f, a3 = 0.f;
  for (int s = 0; s < 256; ++s) {
    float a = attn[b * S_ + s0 + s];
    ushort4 ev = base[(size_t)s * 256];
    a0 += a * bf2f(ev.x); a1 += a * bf2f(ev.y);
    a2 += a * bf2f(ev.z); a3 += a * bf2f(ev.w);
  }
  float* c = ctx + (size_t)b * ENC_ + tid * 4;
  atomicAdd(c + 0, a0); atomicAdd(c + 1, a1);
  atomicAdd(c + 2, a2); atomicAdd(c + 3, a3);
}

extern "C" void kernel_launch(void* const* d_in, const int* in_sizes, int n_in,
                              void* d_out, int out_size, void* d_ws, size_t ws_size,
                              hipStream_t stream) {
  const float* enc  = (const float*)d_in[0];
  const float* dec  = (const float*)d_in[1];
  const int*   mask = (const int*)  d_in[2];
  const float* W    = (const float*)d_in[3];
  const float* U    = (const float*)d_in[4];
  const float* v    = (const float*)d_in[5];

  float* out  = (float*)d_out;
  float* ctx  = out;
  float* attn = out + B_ * ENC_;

  char* ws = (char*)d_ws;
  unsigned short* enc16 = (unsigned short*)ws;                                    // 128MB
  unsigned short* Wt    = (unsigned short*)(ws + (size_t)M_ * ENC_ * 2);          // 2MB
  float* t_buf  = (float*)(ws + (size_t)M_ * ENC_ * 2 + (size_t)ENC_ * DEC_ * 2); // 128KB
  float* scores = (float*)((char*)t_buf + (size_t)B_ * DEC_ * 4);                 // 256KB

  (void)hipFuncSetAttribute((const void*)scores_kernel,
                            hipFuncAttributeMaxDynamicSharedMemorySize, 131072);

  prep_kernel<<<1312, 256, 0, stream>>>(W, dec, U, Wt, t_buf, scores, ctx);

  scores_kernel<<<1024, 512, 131072, stream>>>(enc, Wt, t_buf, v, scores, enc16);

  softmax_kernel<<<B_, 256, 0, stream>>>(scores, mask, attn);

  ctx_kernel<<<dim3(B_, S_ / 256), 256, 0, stream>>>(enc16, attn, ctx);
}

// Round 6
// 258.114 us; speedup vs baseline: 1.6672x; 1.2025x over previous
//
#include <hip/hip_runtime.h>
#include <hip/hip_bf16.h>
#include <stdint.h>

// Problem dims (fixed)
#define B_    32
#define S_    2048
#define ENC_  1024
#define DEC_  1024
#define M_    (B_*S_)   // 65536

typedef __attribute__((ext_vector_type(8))) short bf16x8;
typedef __attribute__((ext_vector_type(4))) float f32x4;

__device__ __forceinline__ unsigned short f2bf(float f) {
  unsigned u = __builtin_bit_cast(unsigned, f);
  u += 0x7FFFu + ((u >> 16) & 1u);            // RNE
  return (unsigned short)(u >> 16);
}
__device__ __forceinline__ float bf2f(unsigned short u) {
  unsigned x = ((unsigned)u) << 16;
  return __builtin_bit_cast(float, x);
}
__device__ __forceinline__ void async_copy16(void* lds_dst, const void* g_src) {
  __builtin_amdgcn_global_load_lds(
      (const __attribute__((address_space(1))) void*)g_src,
      (__attribute__((address_space(3))) void*)lds_dst, 16, 0, 0);
}
__device__ __forceinline__ float tanh_fast(float x) {
  return 1.f - 2.f / (__expf(2.f * x) + 1.f);
}

// ---------- kernel 1: prep = enc cvt + Wt transpose/convert + t = dec@U + zeroing ----------
// blocks [0,8192): enc f32 -> bf16 (the BW long pole, issued first)
// blocks [8192,9216): W -> Wt^T bf16 ; [9216,9472): t = dec@U ; [9472,9504): zero out bufs
__global__ __launch_bounds__(256) void prep_kernel(
    const float* __restrict__ enc, unsigned short* __restrict__ enc16,
    const float* __restrict__ W, const float* __restrict__ dec,
    const float* __restrict__ U, unsigned short* __restrict__ Wt,
    float* __restrict__ t_buf, float* __restrict__ scoresZ,
    float* __restrict__ ctxZ) {
  __shared__ float smem[32 * 33];
  const int blk = blockIdx.x, tid = threadIdx.x;
  if (blk < 8192) {
    // enc: 16M float4 -> ushort4, 2048 float4 per block
    const float4* in = (const float4*)enc;
    ushort4* out = (ushort4*)enc16;
    #pragma unroll
    for (int i = 0; i < 8; ++i) {
      int idx = blk * 2048 + i * 256 + tid;
      float4 f = in[idx];
      ushort4 o;
      o.x = f2bf(f.x); o.y = f2bf(f.y); o.z = f2bf(f.z); o.w = f2bf(f.w);
      out[idx] = o;
    }
  } else if (blk < 9216) {
    // W[e][d] f32 -> Wt[d][e] bf16
    const int q = blk - 8192;
    const int e0 = (q & 31) * 32, d0 = (q >> 5) * 32;
    const int tx = tid & 31, ty = tid >> 5;   // 32 x 8
    #pragma unroll
    for (int i = 0; i < 4; ++i)
      smem[(ty + i*8)*33 + tx] = W[(size_t)(e0 + ty + i*8) * DEC_ + d0 + tx];
    __syncthreads();
    #pragma unroll
    for (int i = 0; i < 4; ++i)
      Wt[(size_t)(d0 + ty + i*8) * ENC_ + e0 + tx] = f2bf(smem[tx*33 + ty + i*8]);
  } else if (blk < 9472) {
    // t[b][d] = dec[b,:] . U[:,d]  (atomic-free: 2 e-halves reduced in LDS)
    const int q = blk - 9216;
    const int dblk = q & 7, b = q >> 3;
    const int d = dblk * 128 + (tid & 127);
    const int h = tid >> 7;
    float acc = 0.f;
    const float* dv = dec + b * DEC_ + h * 512;
    const float* Uc = U + (size_t)(h * 512) * DEC_ + d;
    for (int e = 0; e < 512; ++e) acc += dv[e] * Uc[(size_t)e * DEC_];
    smem[tid] = acc;
    __syncthreads();
    if (tid < 128) t_buf[b * DEC_ + d] = smem[tid] + smem[tid + 128];
  } else {
    // zero scores (65536 f) and ctx (32768 f)
    const int q = blk - 9472;   // 32 blocks
    float4 z = {0.f, 0.f, 0.f, 0.f};
    for (int i = tid; i < 512; i += 256) ((float4*)scoresZ)[q * 512 + i] = z;
    for (int i = tid; i < 256; i += 256) ((float4*)ctxZ)[q * 256 + i] = z;
  }
}

// ---------- kernel 2: fused scores GEMM, 256x256x64, 8-phase (r4-verified) ----------
// 512 threads = 8 waves (2M x 4N), per-wave C = 128x64 (2Q x 4 fragments).
// LDS 128KB: A buf c @ c*32768 (256x64 bf16), B buf c @ 65536 + c*32768.
// T2 swizzle (zero-conflict): 16B-slot ^= row&7 via pre-swizzled global src
// (linear global_load_lds dest) + swizzled ds_read.
// 2 stages/phase; counted vmcnt(4) at phases 4/8 only.

#define WT_L  asm volatile("s_waitcnt lgkmcnt(0)" ::: "memory")
#define WT_V4 asm volatile("s_waitcnt vmcnt(4) lgkmcnt(0)" ::: "memory")
#define WT_V0 asm volatile("s_waitcnt vmcnt(0) lgkmcnt(0)" ::: "memory")

#define PHASE(CBUF, Q, KK, BLOAD, TAILWAIT, ...) do {                       \
    bf16x8 af_[4];                                                          \
    const int aA_ = (KK ? aAddr1 : aAddr0) + (CBUF)*32768 + (Q)*16384;      \
    _Pragma("unroll")                                                       \
    for (int mi = 0; mi < 4; ++mi)                                          \
      af_[mi] = *(const bf16x8*)(lds + aA_ + mi*2048);                      \
    if (BLOAD) {                                                            \
      const int bA_ = (KK ? bAddr1 : bAddr0) + (CBUF)*32768;                \
      _Pragma("unroll")                                                     \
      for (int ni = 0; ni < 4; ++ni)                                        \
        bfr[KK][ni] = *(const bf16x8*)(lds + bA_ + ni*2048);                \
    }                                                                       \
    __VA_ARGS__;                                                            \
    __builtin_amdgcn_s_barrier();                                           \
    __builtin_amdgcn_sched_barrier(0);                                      \
    __builtin_amdgcn_s_setprio(1);                                          \
    _Pragma("unroll")                                                       \
    for (int mi = 0; mi < 4; ++mi) {                                        \
      _Pragma("unroll")                                                     \
      for (int ni = 0; ni < 4; ++ni)                                        \
        acc[(Q)*4+mi][ni] = __builtin_amdgcn_mfma_f32_16x16x32_bf16(        \
            af_[mi], bfr[KK][ni], acc[(Q)*4+mi][ni], 0, 0, 0);              \
    }                                                                       \
    __builtin_amdgcn_s_setprio(0);                                          \
    __builtin_amdgcn_sched_barrier(0);                                      \
    TAILWAIT;                                                               \
    __builtin_amdgcn_s_barrier();                                           \
  } while (0)

__global__ __launch_bounds__(512, 2) void scores_kernel(
    const unsigned short* __restrict__ A,     // enc16 [65536][1024]
    const unsigned short* __restrict__ Bt,    // Wt [1024 n][1024 k]
    const float* __restrict__ tb,
    const float* __restrict__ v,
    float* __restrict__ scores)
{
  extern __shared__ char lds[];

  const int tid  = threadIdx.x;
  const int lane = tid & 63;
  const int wid  = tid >> 6;
  const int wr = wid >> 2, wc = wid & 3;        // 2M x 4N wave grid
  const int fr = lane & 15, fq = lane >> 4;

  // XCD swizzle: bijective (1024 % 8 == 0); 4 n-blocks of one m-panel
  // run concurrently on one XCD -> enc panel L2-shared.
  const int bid = blockIdx.x;
  const int logical = (bid & 7) * 128 + (bid >> 3);
  const int m_blk = logical >> 2, n_blk = logical & 3;
  const int m0 = m_blk << 8;                    // 256 rows
  const int n0 = n_blk << 8;                    // 256 cols
  const int b  = m_blk >> 3;                    // batch (2048 rows / 256)

  // ---- staging source addressing (pre-swizzled global source) ----
  const int srow   = tid >> 3;                          // 0..63
  const int kchunk = (((tid & 7) ^ (srow & 7)) << 3);   // swizzled 16B chunk
  const unsigned short* aP0 = A  + (size_t)(m0       + srow) * ENC_ + kchunk;
  const unsigned short* aP1 = A  + (size_t)(m0 + 64  + srow) * ENC_ + kchunk;
  const unsigned short* aP2 = A  + (size_t)(m0 + 128 + srow) * ENC_ + kchunk;
  const unsigned short* aP3 = A  + (size_t)(m0 + 192 + srow) * ENC_ + kchunk;
  const unsigned short* bP0 = Bt + (size_t)(n0       + srow) * ENC_ + kchunk;
  const unsigned short* bP1 = Bt + (size_t)(n0 + 64  + srow) * ENC_ + kchunk;
  const unsigned short* bP2 = Bt + (size_t)(n0 + 128 + srow) * ENC_ + kchunk;
  const unsigned short* bP3 = Bt + (size_t)(n0 + 192 + srow) * ENC_ + kchunk;
  const int wbase = wid * 1024;                 // wave-uniform LDS dest base

  auto stA = [&](int c, int r, const unsigned short* p) {
    async_copy16(lds + c * 32768 + r * 8192 + wbase, p);
  };
  auto stB = [&](int c, int r, const unsigned short* p) {
    async_copy16(lds + 65536 + c * 32768 + r * 8192 + wbase, p);
  };

  // ---- fragment read addressing (swizzled; further offsets compile-time) ----
  const int sl0 = ((fq)     ^ (fr & 7)) << 4;
  const int sl1 = ((4 + fq) ^ (fr & 7)) << 4;
  const int aAddr0 = (wr * 64 + fr) * 128 + sl0;
  const int aAddr1 = (wr * 64 + fr) * 128 + sl1;
  const int bAddr0 = 65536 + (wc * 64 + fr) * 128 + sl0;
  const int bAddr1 = 65536 + (wc * 64 + fr) * 128 + sl1;

  f32x4 acc[8][4] = {};
  bf16x8 bfr[2][4];

  // ---- prologue: tile0 full -> buf0; tile1 A0,A1,B0,B1 -> buf1 ----
  stA(0, 0, aP0); stA(0, 1, aP1); stA(0, 2, aP2); stA(0, 3, aP3);
  stB(0, 0, bP0); stB(0, 1, bP1); stB(0, 2, bP2); stB(0, 3, bP3);
  stA(1, 0, aP0 + 64); stA(1, 1, aP1 + 64);
  stB(1, 0, bP0 + 64); stB(1, 1, bP1 + 64);
  asm volatile("s_waitcnt vmcnt(4)" ::: "memory");
  __builtin_amdgcn_s_barrier();

  // ---- main loop: iterations 0..6 (pf), 7 peeled ----
  #pragma unroll 1
  for (int J = 0; J < 7; ++J) {
    const int ke = J * 128;
    PHASE(0,0,0,true,  WT_L,  { stB(1,2,bP2+ke+64);  stB(1,3,bP3+ke+64);  });
    PHASE(0,0,1,true,  WT_L,  { stA(1,2,aP2+ke+64);  stA(1,3,aP3+ke+64);  });
    PHASE(0,1,0,false, WT_L,  { stA(0,0,aP0+ke+128); stA(0,1,aP1+ke+128); });
    PHASE(0,1,1,false, WT_V4, { stB(0,0,bP0+ke+128); stB(0,1,bP1+ke+128); });
    PHASE(1,0,0,true,  WT_L,  { stB(0,2,bP2+ke+128); stB(0,3,bP3+ke+128); });
    PHASE(1,0,1,true,  WT_L,  { stA(0,2,aP2+ke+128); stA(0,3,aP3+ke+128); });
    PHASE(1,1,0,false, WT_L,  { stA(1,0,aP0+ke+192); stA(1,1,aP1+ke+192); });
    PHASE(1,1,1,false, WT_V4, { stB(1,0,bP0+ke+192); stB(1,1,bP1+ke+192); });
  }
  {
    const int ke = 896;
    PHASE(0,0,0,true,  WT_L,  { stB(1,2,bP2+ke+64); stB(1,3,bP3+ke+64); });
    PHASE(0,0,1,true,  WT_L,  { stA(1,2,aP2+ke+64); stA(1,3,aP3+ke+64); });
    PHASE(0,1,0,false, WT_L,  {});
    PHASE(0,1,1,false, WT_V0, {});
    PHASE(1,0,0,true,  WT_L,  {});
    PHASE(1,0,1,true,  WT_L,  {});
    PHASE(1,1,0,false, WT_L,  {});
    PHASE(1,1,1,false, WT_V0, {});
  }

  // ---- epilogue: v-dot of tanh(acc + t), row-reduce, atomic to scores ----
  asm volatile("s_waitcnt vmcnt(0) lgkmcnt(0)" ::: "memory");
  __builtin_amdgcn_s_barrier();
  float* sloc = (float*)lds;
  if (tid < 256) sloc[tid] = 0.f;
  __syncthreads();

  float vv[4], tv[4];
  #pragma unroll
  for (int ni = 0; ni < 4; ++ni) {
    int col = n0 + wc * 64 + ni * 16 + fr;
    vv[ni] = v[col];
    tv[ni] = tb[b * DEC_ + col];
  }
  #pragma unroll
  for (int mi = 0; mi < 8; ++mi) {
    #pragma unroll
    for (int j = 0; j < 4; ++j) {
      float p = 0.f;
      #pragma unroll
      for (int ni = 0; ni < 4; ++ni)
        p += vv[ni] * tanh_fast(acc[mi][ni][j] + tv[ni]);
      p += __shfl_xor(p, 1);
      p += __shfl_xor(p, 2);
      p += __shfl_xor(p, 4);
      p += __shfl_xor(p, 8);
      if (fr == 0)
        atomicAdd(&sloc[(mi >> 2) * 128 + wr * 64 + (mi & 3) * 16 + fq * 4 + j], p);
    }
  }
  __syncthreads();
  if (tid < 256) atomicAdd(&scores[m0 + tid], sloc[tid]);
}

// ---------- kernel 3: masked softmax over S per batch ----------
__global__ __launch_bounds__(256) void softmax_kernel(
    const float* __restrict__ scores, const int* __restrict__ mask,
    float* __restrict__ attn) {
  const int b = blockIdx.x;
  const int tid = threadIdx.x;
  const int lane = tid & 63, w = tid >> 6;
  __shared__ float wred[4];
  float loc[8];
  float mx = -3.0e38f;
  #pragma unroll
  for (int i = 0; i < 8; ++i) {
    int s = tid + i * 256;
    float val = (mask[b * S_ + s] == 0) ? -1e9f : scores[b * S_ + s];
    loc[i] = val;
    mx = fmaxf(mx, val);
  }
  #pragma unroll
  for (int m = 1; m < 64; m <<= 1) mx = fmaxf(mx, __shfl_xor(mx, m));
  if (lane == 0) wred[w] = mx;
  __syncthreads();
  mx = fmaxf(fmaxf(wred[0], wred[1]), fmaxf(wred[2], wred[3]));
  __syncthreads();
  float sum = 0.f;
  #pragma unroll
  for (int i = 0; i < 8; ++i) { loc[i] = __expf(loc[i] - mx); sum += loc[i]; }
  #pragma unroll
  for (int m = 1; m < 64; m <<= 1) sum += __shfl_xor(sum, m);
  if (lane == 0) wred[w] = sum;
  __syncthreads();
  float inv = 1.f / (wred[0] + wred[1] + wred[2] + wred[3]);
  #pragma unroll
  for (int i = 0; i < 8; ++i) attn[b * S_ + tid + i * 256] = loc[i] * inv;
}

// ---------- kernel 4: context[b,e] = sum_s attn[b,s]*enc16[b,s,e] ----------
__global__ __launch_bounds__(256) void ctx_kernel(
    const unsigned short* __restrict__ enc16,
    const float* __restrict__ attn,
    float* __restrict__ ctx) {
  const int b  = blockIdx.x;
  const int s0 = blockIdx.y * 256;
  const int tid = threadIdx.x;
  const ushort4* base = reinterpret_cast<const ushort4*>(
      enc16 + ((size_t)b * S_ + s0) * ENC_) + tid;
  float a0 = 0.f, a1 = 0.f, a2 = 0.f, a3 = 0.f;
  for (int s = 0; s < 256; ++s) {
    float a = attn[b * S_ + s0 + s];
    ushort4 ev = base[(size_t)s * 256];
    a0 += a * bf2f(ev.x); a1 += a * bf2f(ev.y);
    a2 += a * bf2f(ev.z); a3 += a * bf2f(ev.w);
  }
  float* c = ctx + (size_t)b * ENC_ + tid * 4;
  atomicAdd(c + 0, a0); atomicAdd(c + 1, a1);
  atomicAdd(c + 2, a2); atomicAdd(c + 3, a3);
}

extern "C" void kernel_launch(void* const* d_in, const int* in_sizes, int n_in,
                              void* d_out, int out_size, void* d_ws, size_t ws_size,
                              hipStream_t stream) {
  const float* enc  = (const float*)d_in[0];
  const float* dec  = (const float*)d_in[1];
  const int*   mask = (const int*)  d_in[2];
  const float* W    = (const float*)d_in[3];
  const float* U    = (const float*)d_in[4];
  const float* v    = (const float*)d_in[5];

  float* out  = (float*)d_out;
  float* ctx  = out;
  float* attn = out + B_ * ENC_;

  char* ws = (char*)d_ws;
  unsigned short* enc16 = (unsigned short*)ws;                                    // 128MB
  unsigned short* Wt    = (unsigned short*)(ws + (size_t)M_ * ENC_ * 2);          // 2MB
  float* t_buf  = (float*)(ws + (size_t)M_ * ENC_ * 2 + (size_t)ENC_ * DEC_ * 2); // 128KB
  float* scores = (float*)((char*)t_buf + (size_t)B_ * DEC_ * 4);                 // 256KB

  (void)hipFuncSetAttribute((const void*)scores_kernel,
                            hipFuncAttributeMaxDynamicSharedMemorySize, 131072);

  prep_kernel<<<9504, 256, 0, stream>>>(enc, enc16, W, dec, U, Wt,
                                        t_buf, scores, ctx);

  scores_kernel<<<1024, 512, 131072, stream>>>(enc16, Wt, t_buf, v, scores);

  softmax_kernel<<<B_, 256, 0, stream>>>(scores, mask, attn);

  ctx_kernel<<<dim3(B_, S_ / 256), 256, 0, stream>>>(enc16, attn, ctx);
}

// Round 7
// 249.032 us; speedup vs baseline: 1.7280x; 1.0365x over previous
//
#include <hip/hip_runtime.h>
#include <hip/hip_bf16.h>
#include <stdint.h>

// Problem dims (fixed)
#define B_    32
#define S_    2048
#define ENC_  1024
#define DEC_  1024
#define M_    (B_*S_)   // 65536

typedef __attribute__((ext_vector_type(8))) short bf16x8;
typedef __attribute__((ext_vector_type(4))) float f32x4;
typedef __attribute__((ext_vector_type(8))) unsigned short u16x8;

__device__ __forceinline__ unsigned short f2bf(float f) {
  unsigned u = __builtin_bit_cast(unsigned, f);
  u += 0x7FFFu + ((u >> 16) & 1u);            // RNE
  return (unsigned short)(u >> 16);
}
__device__ __forceinline__ float bf2f(unsigned short u) {
  unsigned x = ((unsigned)u) << 16;
  return __builtin_bit_cast(float, x);
}
__device__ __forceinline__ void async_copy16(void* lds_dst, const void* g_src) {
  __builtin_amdgcn_global_load_lds(
      (const __attribute__((address_space(1))) void*)g_src,
      (__attribute__((address_space(3))) void*)lds_dst, 16, 0, 0);
}
__device__ __forceinline__ float tanh_fast(float x) {
  return 1.f - 2.f / (__expf(2.f * x) + 1.f);
}

// ---------- kernel 1: prep ----------
// blocks [0,1024): W -> Wt^T bf16 ; [1024,1280): t = dec@U ;
// [1280,1312): zero scores/ctx ; [1312, 9504): enc f32 -> bf16 (BW long pole,
// placed LAST so the small blocks don't become a serial tail).
__global__ __launch_bounds__(256) void prep_kernel(
    const float* __restrict__ enc, unsigned short* __restrict__ enc16,
    const float* __restrict__ W, const float* __restrict__ dec,
    const float* __restrict__ U, unsigned short* __restrict__ Wt,
    float* __restrict__ t_buf, float* __restrict__ scoresZ,
    float* __restrict__ ctxZ) {
  __shared__ float smem[32 * 33];
  const int blk = blockIdx.x, tid = threadIdx.x;
  if (blk < 1024) {
    // W[e][d] f32 -> Wt[d][e] bf16
    const int e0 = (blk & 31) * 32, d0 = (blk >> 5) * 32;
    const int tx = tid & 31, ty = tid >> 5;   // 32 x 8
    #pragma unroll
    for (int i = 0; i < 4; ++i)
      smem[(ty + i*8)*33 + tx] = W[(size_t)(e0 + ty + i*8) * DEC_ + d0 + tx];
    __syncthreads();
    #pragma unroll
    for (int i = 0; i < 4; ++i)
      Wt[(size_t)(d0 + ty + i*8) * ENC_ + e0 + tx] = f2bf(smem[tx*33 + ty + i*8]);
  } else if (blk < 1280) {
    // t[b][d] = dec[b,:] . U[:,d]  (atomic-free: 2 e-halves reduced in LDS)
    const int q = blk - 1024;
    const int dblk = q & 7, b = q >> 3;
    const int d = dblk * 128 + (tid & 127);
    const int h = tid >> 7;
    float acc = 0.f;
    const float* dv = dec + b * DEC_ + h * 512;
    const float* Uc = U + (size_t)(h * 512) * DEC_ + d;
    for (int e = 0; e < 512; ++e) acc += dv[e] * Uc[(size_t)e * DEC_];
    smem[tid] = acc;
    __syncthreads();
    if (tid < 128) t_buf[b * DEC_ + d] = smem[tid] + smem[tid + 128];
  } else if (blk < 1312) {
    // zero scores (65536 f) and ctx (32768 f)
    const int q = blk - 1280;   // 32 blocks
    float4 z = {0.f, 0.f, 0.f, 0.f};
    for (int i = tid; i < 512; i += 256) ((float4*)scoresZ)[q * 512 + i] = z;
    for (int i = tid; i < 256; i += 256) ((float4*)ctxZ)[q * 256 + i] = z;
  } else {
    // enc: 8.39M ushort8 outputs, 1024 per block (8192 blocks)
    const int q = blk - 1312;
    const float4* in = (const float4*)enc;
    u16x8* out = (u16x8*)enc16;
    #pragma unroll
    for (int i = 0; i < 4; ++i) {
      int u = q * 1024 + i * 256 + tid;
      float4 f0 = in[2*u], f1 = in[2*u + 1];
      u16x8 o;
      o[0] = f2bf(f0.x); o[1] = f2bf(f0.y); o[2] = f2bf(f0.z); o[3] = f2bf(f0.w);
      o[4] = f2bf(f1.x); o[5] = f2bf(f1.y); o[6] = f2bf(f1.z); o[7] = f2bf(f1.w);
      out[u] = o;
    }
  }
}

// ---------- kernel 2: fused scores GEMM, 256x256x64, 8-phase (r4/r6-verified) ----------
// 512 threads = 8 waves (2M x 4N), per-wave C = 128x64 (2Q x 4 fragments).
// LDS 128KB: A buf c @ c*32768 (256x64 bf16), B buf c @ 65536 + c*32768.
// T2 swizzle (zero-conflict): 16B-slot ^= row&7 via pre-swizzled global src
// (linear global_load_lds dest) + swizzled ds_read.
// 2 stages/phase; counted vmcnt(4) at phases 4/8 only.

#define WT_L  asm volatile("s_waitcnt lgkmcnt(0)" ::: "memory")
#define WT_V4 asm volatile("s_waitcnt vmcnt(4) lgkmcnt(0)" ::: "memory")
#define WT_V0 asm volatile("s_waitcnt vmcnt(0) lgkmcnt(0)" ::: "memory")

#define PHASE(CBUF, Q, KK, BLOAD, TAILWAIT, ...) do {                       \
    bf16x8 af_[4];                                                          \
    const int aA_ = (KK ? aAddr1 : aAddr0) + (CBUF)*32768 + (Q)*16384;      \
    _Pragma("unroll")                                                       \
    for (int mi = 0; mi < 4; ++mi)                                          \
      af_[mi] = *(const bf16x8*)(lds + aA_ + mi*2048);                      \
    if (BLOAD) {                                                            \
      const int bA_ = (KK ? bAddr1 : bAddr0) + (CBUF)*32768;                \
      _Pragma("unroll")                                                     \
      for (int ni = 0; ni < 4; ++ni)                                        \
        bfr[KK][ni] = *(const bf16x8*)(lds + bA_ + ni*2048);                \
    }                                                                       \
    __VA_ARGS__;                                                            \
    __builtin_amdgcn_s_barrier();                                           \
    __builtin_amdgcn_sched_barrier(0);                                      \
    __builtin_amdgcn_s_setprio(1);                                          \
    _Pragma("unroll")                                                       \
    for (int mi = 0; mi < 4; ++mi) {                                        \
      _Pragma("unroll")                                                     \
      for (int ni = 0; ni < 4; ++ni)                                        \
        acc[(Q)*4+mi][ni] = __builtin_amdgcn_mfma_f32_16x16x32_bf16(        \
            af_[mi], bfr[KK][ni], acc[(Q)*4+mi][ni], 0, 0, 0);              \
    }                                                                       \
    __builtin_amdgcn_s_setprio(0);                                          \
    __builtin_amdgcn_sched_barrier(0);                                      \
    TAILWAIT;                                                               \
    __builtin_amdgcn_s_barrier();                                           \
  } while (0)

__global__ __launch_bounds__(512, 2) void scores_kernel(
    const unsigned short* __restrict__ A,     // enc16 [65536][1024]
    const unsigned short* __restrict__ Bt,    // Wt [1024 n][1024 k]
    const float* __restrict__ tb,
    const float* __restrict__ v,
    float* __restrict__ scores)
{
  extern __shared__ char lds[];

  const int tid  = threadIdx.x;
  const int lane = tid & 63;
  const int wid  = tid >> 6;
  const int wr = wid >> 2, wc = wid & 3;        // 2M x 4N wave grid
  const int fr = lane & 15, fq = lane >> 4;

  // XCD swizzle: bijective (1024 % 8 == 0); 4 n-blocks of one m-panel
  // run concurrently on one XCD -> enc panel L2-shared.
  const int bid = blockIdx.x;
  const int logical = (bid & 7) * 128 + (bid >> 3);
  const int m_blk = logical >> 2, n_blk = logical & 3;
  const int m0 = m_blk << 8;                    // 256 rows
  const int n0 = n_blk << 8;                    // 256 cols
  const int b  = m_blk >> 3;                    // batch (2048 rows / 256)

  // ---- staging source addressing (pre-swizzled global source) ----
  const int srow   = tid >> 3;                          // 0..63
  const int kchunk = (((tid & 7) ^ (srow & 7)) << 3);   // swizzled 16B chunk
  const unsigned short* aP0 = A  + (size_t)(m0       + srow) * ENC_ + kchunk;
  const unsigned short* aP1 = A  + (size_t)(m0 + 64  + srow) * ENC_ + kchunk;
  const unsigned short* aP2 = A  + (size_t)(m0 + 128 + srow) * ENC_ + kchunk;
  const unsigned short* aP3 = A  + (size_t)(m0 + 192 + srow) * ENC_ + kchunk;
  const unsigned short* bP0 = Bt + (size_t)(n0       + srow) * ENC_ + kchunk;
  const unsigned short* bP1 = Bt + (size_t)(n0 + 64  + srow) * ENC_ + kchunk;
  const unsigned short* bP2 = Bt + (size_t)(n0 + 128 + srow) * ENC_ + kchunk;
  const unsigned short* bP3 = Bt + (size_t)(n0 + 192 + srow) * ENC_ + kchunk;
  const int wbase = wid * 1024;                 // wave-uniform LDS dest base

  auto stA = [&](int c, int r, const unsigned short* p) {
    async_copy16(lds + c * 32768 + r * 8192 + wbase, p);
  };
  auto stB = [&](int c, int r, const unsigned short* p) {
    async_copy16(lds + 65536 + c * 32768 + r * 8192 + wbase, p);
  };

  // ---- fragment read addressing (swizzled; further offsets compile-time) ----
  const int sl0 = ((fq)     ^ (fr & 7)) << 4;
  const int sl1 = ((4 + fq) ^ (fr & 7)) << 4;
  const int aAddr0 = (wr * 64 + fr) * 128 + sl0;
  const int aAddr1 = (wr * 64 + fr) * 128 + sl1;
  const int bAddr0 = 65536 + (wc * 64 + fr) * 128 + sl0;
  const int bAddr1 = 65536 + (wc * 64 + fr) * 128 + sl1;

  f32x4 acc[8][4] = {};
  bf16x8 bfr[2][4];

  // ---- prologue: tile0 full -> buf0; tile1 A0,A1,B0,B1 -> buf1 ----
  stA(0, 0, aP0); stA(0, 1, aP1); stA(0, 2, aP2); stA(0, 3, aP3);
  stB(0, 0, bP0); stB(0, 1, bP1); stB(0, 2, bP2); stB(0, 3, bP3);
  stA(1, 0, aP0 + 64); stA(1, 1, aP1 + 64);
  stB(1, 0, bP0 + 64); stB(1, 1, bP1 + 64);
  asm volatile("s_waitcnt vmcnt(4)" ::: "memory");
  __builtin_amdgcn_s_barrier();

  // ---- main loop: iterations 0..6 (pf), 7 peeled ----
  #pragma unroll 1
  for (int J = 0; J < 7; ++J) {
    const int ke = J * 128;
    PHASE(0,0,0,true,  WT_L,  { stB(1,2,bP2+ke+64);  stB(1,3,bP3+ke+64);  });
    PHASE(0,0,1,true,  WT_L,  { stA(1,2,aP2+ke+64);  stA(1,3,aP3+ke+64);  });
    PHASE(0,1,0,false, WT_L,  { stA(0,0,aP0+ke+128); stA(0,1,aP1+ke+128); });
    PHASE(0,1,1,false, WT_V4, { stB(0,0,bP0+ke+128); stB(0,1,bP1+ke+128); });
    PHASE(1,0,0,true,  WT_L,  { stB(0,2,bP2+ke+128); stB(0,3,bP3+ke+128); });
    PHASE(1,0,1,true,  WT_L,  { stA(0,2,aP2+ke+128); stA(0,3,aP3+ke+128); });
    PHASE(1,1,0,false, WT_L,  { stA(1,0,aP0+ke+192); stA(1,1,aP1+ke+192); });
    PHASE(1,1,1,false, WT_V4, { stB(1,0,bP0+ke+192); stB(1,1,bP1+ke+192); });
  }
  {
    const int ke = 896;
    PHASE(0,0,0,true,  WT_L,  { stB(1,2,bP2+ke+64); stB(1,3,bP3+ke+64); });
    PHASE(0,0,1,true,  WT_L,  { stA(1,2,aP2+ke+64); stA(1,3,aP3+ke+64); });
    PHASE(0,1,0,false, WT_L,  {});
    PHASE(0,1,1,false, WT_V0, {});
    PHASE(1,0,0,true,  WT_L,  {});
    PHASE(1,0,1,true,  WT_L,  {});
    PHASE(1,1,0,false, WT_L,  {});
    PHASE(1,1,1,false, WT_V0, {});
  }

  // ---- epilogue: v-dot of tanh(acc + t), row-reduce, atomic to scores ----
  asm volatile("s_waitcnt vmcnt(0) lgkmcnt(0)" ::: "memory");
  __builtin_amdgcn_s_barrier();
  float* sloc = (float*)lds;
  if (tid < 256) sloc[tid] = 0.f;
  __syncthreads();

  float vv[4], tv[4];
  #pragma unroll
  for (int ni = 0; ni < 4; ++ni) {
    int col = n0 + wc * 64 + ni * 16 + fr;
    vv[ni] = v[col];
    tv[ni] = tb[b * DEC_ + col];
  }
  #pragma unroll
  for (int mi = 0; mi < 8; ++mi) {
    #pragma unroll
    for (int j = 0; j < 4; ++j) {
      float p = 0.f;
      #pragma unroll
      for (int ni = 0; ni < 4; ++ni)
        p += vv[ni] * tanh_fast(acc[mi][ni][j] + tv[ni]);
      p += __shfl_xor(p, 1);
      p += __shfl_xor(p, 2);
      p += __shfl_xor(p, 4);
      p += __shfl_xor(p, 8);
      if (fr == 0)
        atomicAdd(&sloc[(mi >> 2) * 128 + wr * 64 + (mi & 3) * 16 + fq * 4 + j], p);
    }
  }
  __syncthreads();
  if (tid < 256) atomicAdd(&scores[m0 + tid], sloc[tid]);
}

// ---------- kernel 3: fused masked-softmax + context ----------
// grid (B, 16): each block recomputes the full softmax row for batch b
// (reads scores+mask, 16 KB — L2-resident, redundant x16 = trivial), then
// accumulates its 128-s chunk into ctx. y==0 blocks also write attn out.
__global__ __launch_bounds__(256) void sm_ctx_kernel(
    const float* __restrict__ scores, const int* __restrict__ mask,
    const unsigned short* __restrict__ enc16,
    float* __restrict__ attn, float* __restrict__ ctx) {
  const int b = blockIdx.x, y = blockIdx.y;
  const int tid = threadIdx.x;
  const int lane = tid & 63, w = tid >> 6;
  __shared__ float att[S_];
  __shared__ float wred[4];
  float loc[8];
  float mx = -3.0e38f;
  #pragma unroll
  for (int i = 0; i < 8; ++i) {
    int s = tid + i * 256;
    float val = (mask[b * S_ + s] == 0) ? -1e9f : scores[b * S_ + s];
    loc[i] = val;
    mx = fmaxf(mx, val);
  }
  #pragma unroll
  for (int m = 1; m < 64; m <<= 1) mx = fmaxf(mx, __shfl_xor(mx, m));
  if (lane == 0) wred[w] = mx;
  __syncthreads();
  mx = fmaxf(fmaxf(wred[0], wred[1]), fmaxf(wred[2], wred[3]));
  __syncthreads();
  float sum = 0.f;
  #pragma unroll
  for (int i = 0; i < 8; ++i) { loc[i] = __expf(loc[i] - mx); sum += loc[i]; }
  #pragma unroll
  for (int m = 1; m < 64; m <<= 1) sum += __shfl_xor(sum, m);
  if (lane == 0) wred[w] = sum;
  __syncthreads();
  float inv = 1.f / (wred[0] + wred[1] + wred[2] + wred[3]);
  #pragma unroll
  for (int i = 0; i < 8; ++i) {
    float a = loc[i] * inv;
    att[tid + i * 256] = a;
    if (y == 0) attn[b * S_ + tid + i * 256] = a;
  }
  __syncthreads();

  const int s0 = y * 128;
  const ushort4* base = reinterpret_cast<const ushort4*>(
      enc16 + ((size_t)b * S_ + s0) * ENC_) + tid;
  float a0 = 0.f, a1 = 0.f, a2 = 0.f, a3 = 0.f;
  #pragma unroll 4
  for (int s = 0; s < 128; ++s) {
    float a = att[s0 + s];
    ushort4 ev = base[(size_t)s * 256];
    a0 += a * bf2f(ev.x); a1 += a * bf2f(ev.y);
    a2 += a * bf2f(ev.z); a3 += a * bf2f(ev.w);
  }
  float* c = ctx + (size_t)b * ENC_ + tid * 4;
  atomicAdd(c + 0, a0); atomicAdd(c + 1, a1);
  atomicAdd(c + 2, a2); atomicAdd(c + 3, a3);
}

extern "C" void kernel_launch(void* const* d_in, const int* in_sizes, int n_in,
                              void* d_out, int out_size, void* d_ws, size_t ws_size,
                              hipStream_t stream) {
  const float* enc  = (const float*)d_in[0];
  const float* dec  = (const float*)d_in[1];
  const int*   mask = (const int*)  d_in[2];
  const float* W    = (const float*)d_in[3];
  const float* U    = (const float*)d_in[4];
  const float* v    = (const float*)d_in[5];

  float* out  = (float*)d_out;
  float* ctx  = out;
  float* attn = out + B_ * ENC_;

  char* ws = (char*)d_ws;
  unsigned short* enc16 = (unsigned short*)ws;                                    // 128MB
  unsigned short* Wt    = (unsigned short*)(ws + (size_t)M_ * ENC_ * 2);          // 2MB
  float* t_buf  = (float*)(ws + (size_t)M_ * ENC_ * 2 + (size_t)ENC_ * DEC_ * 2); // 128KB
  float* scores = (float*)((char*)t_buf + (size_t)B_ * DEC_ * 4);                 // 256KB

  (void)hipFuncSetAttribute((const void*)scores_kernel,
                            hipFuncAttributeMaxDynamicSharedMemorySize, 131072);

  prep_kernel<<<9504, 256, 0, stream>>>(enc, enc16, W, dec, U, Wt,
                                        t_buf, scores, ctx);

  scores_kernel<<<1024, 512, 131072, stream>>>(enc16, Wt, t_buf, v, scores);

  sm_ctx_kernel<<<dim3(B_, 16), 256, 0, stream>>>(scores, mask, enc16, attn, ctx);
}